// Round 1
// baseline (909.529 us; speedup 1.0000x reference)
//
#include <hip/hip_runtime.h>
#include <cstdint>
#include <cstddef>

// Problem constants (from reference): IN=512, H=8, C=8, HID=64, OUT=64
#define LEAKY 0.2f
static const int CHUNK = 2048;   // scan chunk per block (256 thr * 8)

__device__ __forceinline__ float dot4(float4 a, float4 b) {
    return a.x * b.x + a.y * b.y + a.z * b.z + a.w * b.w;
}

// ---------------------------------------------------------------- CSR build
__global__ __launch_bounds__(256) void k_init_deg(int* __restrict__ deg, int Nn) {
    int i = blockIdx.x * 256 + threadIdx.x;
    if (i < Nn) deg[i] = 1;              // self-loop
}

__global__ __launch_bounds__(256) void k_count(const int* __restrict__ ei, int* __restrict__ deg, int E) {
    int e = blockIdx.x * 256 + threadIdx.x;
    if (e < E) atomicAdd(&deg[ei[E + e]], 1);   // ei[1][e] = dst
}

__global__ __launch_bounds__(256) void k_scan1(const int* __restrict__ deg, int* __restrict__ bsum, int Nn) {
    __shared__ int sm[256];
    int b = blockIdx.x, t = threadIdx.x;
    int s = 0;
    int i0 = b * CHUNK + t * 8;
#pragma unroll
    for (int j = 0; j < 8; ++j) { int i = i0 + j; if (i < Nn) s += deg[i]; }
    sm[t] = s;
    __syncthreads();
    for (int o = 128; o; o >>= 1) { if (t < o) sm[t] += sm[t + o]; __syncthreads(); }
    if (t == 0) bsum[b] = sm[0];
}

__global__ void k_scan2(const int* __restrict__ bsum, int* __restrict__ bpre, int B) {
    int l = threadIdx.x;            // 64 threads, B <= 64
    int v = (l < B) ? bsum[l] : 0;
    int inc = v;
#pragma unroll
    for (int o = 1; o < 64; o <<= 1) { int u = __shfl_up(inc, o); if (l >= o) inc += u; }
    if (l < B) bpre[l] = inc - v;   // exclusive
}

__global__ __launch_bounds__(256) void k_scan3(const int* __restrict__ deg, const int* __restrict__ bpre,
                                               int* __restrict__ indptr, int* __restrict__ cursor, int Nn) {
    __shared__ int wsum[4];
    int b = blockIdx.x, t = threadIdx.x, lane = t & 63, w = t >> 6;
    int i0 = b * CHUNK + t * 8;
    int d[8]; int s = 0;
#pragma unroll
    for (int j = 0; j < 8; ++j) { int i = i0 + j; d[j] = (i < Nn) ? deg[i] : 0; s += d[j]; }
    int inc = s;
#pragma unroll
    for (int o = 1; o < 64; o <<= 1) { int u = __shfl_up(inc, o); if (lane >= o) inc += u; }
    if (lane == 63) wsum[w] = inc;
    __syncthreads();
    int wofs = 0;
    for (int k = 0; k < w; ++k) wofs += wsum[k];
    int base = bpre[b] + wofs + (inc - s);
    int run = 0;
#pragma unroll
    for (int j = 0; j < 8; ++j) {
        int i = i0 + j;
        if (i < Nn) {
            int v = base + run;
            indptr[i] = v; cursor[i] = v;
            run += d[j];
            if (i == Nn - 1) indptr[Nn] = v + d[j];
        }
    }
}

__global__ __launch_bounds__(256) void k_fill(const int* __restrict__ ei, int* __restrict__ cursor,
                                              int* __restrict__ csr, int E, int Nn) {
    int idx = blockIdx.x * 256 + threadIdx.x;
    if (idx >= E + Nn) return;
    int s, d;
    if (idx < E) { s = ei[idx]; d = ei[E + idx]; }
    else         { s = idx - E; d = s; }
    int slot = atomicAdd(&cursor[d], 1);
    csr[slot] = s;
}

// ---------------------------------------------------------------- SGEMM C[M,64] = A[M,K] @ B[K,64]
template <int KB>
__global__ __launch_bounds__(256) void gemm_n64(const float* __restrict__ A, const float* __restrict__ B,
                                                float* __restrict__ C, int M, int K) {
    __shared__ float As[KB][68];   // transposed: As[kk][r], pad 68 keeps 16B align
    __shared__ float Bs[KB][68];   // Bs[kk][c]
    int tid = threadIdx.x;
    int row0 = blockIdx.x * 64;
    int tx = tid & 15, ty = tid >> 4;
    float acc[4][4] = {};
    for (int k0 = 0; k0 < K; k0 += KB) {
        // A tile: 64 rows x KB cols; KB/4 float4 per row
#pragma unroll
        for (int j = 0; j < (64 * KB) / (256 * 4); ++j) {
            int f = tid + 256 * j;
            int r = f / (KB / 4);
            int c4 = f % (KB / 4);
            int rg = row0 + r; if (rg >= M) rg = M - 1;
            float4 v = *(const float4*)(A + (size_t)rg * K + k0 + c4 * 4);
            As[c4 * 4 + 0][r] = v.x; As[c4 * 4 + 1][r] = v.y;
            As[c4 * 4 + 2][r] = v.z; As[c4 * 4 + 3][r] = v.w;
        }
        // B tile: KB rows x 64 cols
#pragma unroll
        for (int j = 0; j < (KB * 64) / (256 * 4); ++j) {
            int f = tid + 256 * j;
            int kk = f / 16, c4 = f % 16;
            *(float4*)&Bs[kk][c4 * 4] = *(const float4*)(B + (size_t)(k0 + kk) * 64 + c4 * 4);
        }
        __syncthreads();
#pragma unroll
        for (int kk = 0; kk < KB; ++kk) {
            float4 a = *(const float4*)&As[kk][ty * 4];
            float4 b = *(const float4*)&Bs[kk][tx * 4];
            float av[4] = {a.x, a.y, a.z, a.w};
            float bv[4] = {b.x, b.y, b.z, b.w};
#pragma unroll
            for (int i = 0; i < 4; ++i)
#pragma unroll
                for (int j = 0; j < 4; ++j) acc[i][j] += av[i] * bv[j];
        }
        __syncthreads();
    }
#pragma unroll
    for (int i = 0; i < 4; ++i) {
        int rg = row0 + ty * 4 + i;
        if (rg < M) {
            float4 v = make_float4(acc[i][0], acc[i][1], acc[i][2], acc[i][3]);
            *(float4*)(C + (size_t)rg * 64 + tx * 4) = v;
        }
    }
}

// ---------------------------------------------------------------- attention half-scores
__global__ __launch_bounds__(256) void k_sc1(const float* __restrict__ h1, const float* __restrict__ as1,
                                             const float* __restrict__ ad1, float* __restrict__ scs,
                                             float* __restrict__ scd, int Nn) {
    int i = blockIdx.x * 256 + threadIdx.x;   // i = node*8 + head
    if (i >= Nn * 8) return;
    int h = i & 7;
    const float4* hp = (const float4*)(h1 + (size_t)i * 8);   // node*64 + h*8
    float4 v0 = hp[0], v1 = hp[1];
    const float4* asp = (const float4*)(as1 + h * 8);
    const float4* adp = (const float4*)(ad1 + h * 8);
    scs[i] = dot4(v0, asp[0]) + dot4(v1, asp[1]);
    scd[i] = dot4(v0, adp[0]) + dot4(v1, adp[1]);
}

__global__ __launch_bounds__(256) void k_sc2(const float* __restrict__ h2, const float* __restrict__ as2,
                                             const float* __restrict__ ad2, float* __restrict__ scs,
                                             float* __restrict__ scd, int Nn) {
    int wave = (blockIdx.x * 256 + threadIdx.x) >> 6;
    int lane = threadIdx.x & 63;
    if (wave >= Nn) return;
    float v = h2[(size_t)wave * 64 + lane];
    float ss = v * as2[lane], sd = v * ad2[lane];
#pragma unroll
    for (int o = 32; o; o >>= 1) { ss += __shfl_xor(ss, o); sd += __shfl_xor(sd, o); }
    if (lane == 0) { scs[wave] = ss; scd[wave] = sd; }
}

// ---------------------------------------------------------------- conv1 aggregation (8 heads x 8 ch) -> elu -> x2
__global__ __launch_bounds__(256) void k_agg1(const float* __restrict__ h1, const float* __restrict__ scs,
                                              const float* __restrict__ scd, const int* __restrict__ indptr,
                                              const int* __restrict__ csr, const float* __restrict__ b1,
                                              float* __restrict__ x2, int Nn) {
    int node = (blockIdx.x * 256 + threadIdx.x) >> 6;
    int lane = threadIdx.x & 63;
    if (node >= Nn) return;
    int head = lane >> 3;
    int start = indptr[node], end = indptr[node + 1];
    float sdi = scd[node * 8 + head];

    float mx = -3.402823466e38f;
    for (int base = start; base < end; base += 64) {
        int e = base + lane;
        int s_l = (e < end) ? csr[e] : 0;
        int cnt = min(64, end - base);
#pragma unroll 4
        for (int j = 0; j < cnt; ++j) {
            int s = __shfl(s_l, j);
            float v = scs[s * 8 + head] + sdi;
            v = v > 0.f ? v : LEAKY * v;
            mx = fmaxf(mx, v);
        }
    }
    float acc = 0.f, dsum = 0.f;
    for (int base = start; base < end; base += 64) {
        int e = base + lane;
        int s_l = (e < end) ? csr[e] : 0;
        int cnt = min(64, end - base);
#pragma unroll 4
        for (int j = 0; j < cnt; ++j) {
            int s = __shfl(s_l, j);
            float v = scs[s * 8 + head] + sdi;
            v = v > 0.f ? v : LEAKY * v;
            float ex = __expf(v - mx);
            dsum += ex;
            acc += ex * h1[(size_t)s * 64 + lane];
        }
    }
    float o = acc / (dsum + 1e-16f) + b1[lane];
    o = o > 0.f ? o : expm1f(o);            // elu
    x2[(size_t)node * 64 + lane] = o;
}

// ---------------------------------------------------------------- conv2 aggregation (1 head) -> log_softmax -> out
__global__ __launch_bounds__(256) void k_agg2(const float* __restrict__ h2, const float* __restrict__ scs,
                                              const float* __restrict__ scd, const int* __restrict__ indptr,
                                              const int* __restrict__ csr, const float* __restrict__ b2,
                                              float* __restrict__ out, int Nn) {
    int node = (blockIdx.x * 256 + threadIdx.x) >> 6;
    int lane = threadIdx.x & 63;
    if (node >= Nn) return;
    int start = indptr[node], end = indptr[node + 1];
    float sdi = scd[node];

    // pass 1: max (lane-parallel over edges, then reduce)
    float mx = -3.402823466e38f;
    for (int base = start; base < end; base += 64) {
        int e = base + lane;
        if (e < end) {
            float v = scs[csr[e]] + sdi;
            v = v > 0.f ? v : LEAKY * v;
            mx = fmaxf(mx, v);
        }
    }
#pragma unroll
    for (int o = 32; o; o >>= 1) mx = fmaxf(mx, __shfl_xor(mx, o));

    // pass 2: weighted aggregate (lane = feature)
    float acc = 0.f, dsum = 0.f;
    for (int base = start; base < end; base += 64) {
        int e = base + lane;
        int s_l = (e < end) ? csr[e] : 0;
        int cnt = min(64, end - base);
#pragma unroll 4
        for (int j = 0; j < cnt; ++j) {
            int s = __shfl(s_l, j);
            float v = scs[s] + sdi;
            v = v > 0.f ? v : LEAKY * v;
            float ex = __expf(v - mx);
            dsum += ex;
            acc += ex * h2[(size_t)s * 64 + lane];
        }
    }
    float o = acc / (dsum + 1e-16f) + b2[lane];

    // log_softmax over 64 lanes
    float m2 = o;
#pragma unroll
    for (int d = 32; d; d >>= 1) m2 = fmaxf(m2, __shfl_xor(m2, d));
    float e = __expf(o - m2);
    float se = e;
#pragma unroll
    for (int d = 32; d; d >>= 1) se += __shfl_xor(se, d);
    out[(size_t)node * 64 + lane] = o - m2 - __logf(se);
}

// ---------------------------------------------------------------- launch
extern "C" void kernel_launch(void* const* d_in, const int* in_sizes, int n_in,
                              void* d_out, int out_size, void* d_ws, size_t ws_size,
                              hipStream_t stream) {
    (void)n_in; (void)out_size; (void)ws_size;
    const float* x   = (const float*)d_in[0];
    const int*   ei  = (const int*)d_in[1];
    const float* W1  = (const float*)d_in[2];
    const float* as1 = (const float*)d_in[3];
    const float* ad1 = (const float*)d_in[4];
    const float* b1  = (const float*)d_in[5];
    const float* W2  = (const float*)d_in[6];
    const float* as2 = (const float*)d_in[7];
    const float* ad2 = (const float*)d_in[8];
    const float* b2  = (const float*)d_in[9];
    float* out = (float*)d_out;

    const int N = in_sizes[0] / 512;
    const int E = in_sizes[1] / 2;

    char* p = (char*)d_ws;
    auto alloc = [&](size_t bytes) -> char* {
        char* r = p; p += (bytes + 255) & ~(size_t)255; return r;
    };
    float* h1    = (float*)alloc((size_t)N * 64 * 4);
    float* x2    = (float*)alloc((size_t)N * 64 * 4);
    float* h2    = h1;                 // overlay: h1 dead after k_agg1
    float* sc1s  = (float*)alloc((size_t)N * 8 * 4);
    float* sc1d  = (float*)alloc((size_t)N * 8 * 4);
    float* sc2s  = (float*)alloc((size_t)N * 4);
    float* sc2d  = (float*)alloc((size_t)N * 4);
    int*   deg   = (int*)alloc((size_t)N * 4);
    int*   cursor= (int*)alloc((size_t)N * 4);
    int*   indptr= (int*)alloc((size_t)(N + 1) * 4);
    int*   csr   = (int*)alloc((size_t)(E + N) * 4);
    int*   bsum  = (int*)alloc(64 * 4);
    int*   bpre  = (int*)alloc(64 * 4);

    const int B = (N + CHUNK - 1) / CHUNK;     // 49 <= 64

    // CSR build
    k_init_deg<<<(N + 255) / 256, 256, 0, stream>>>(deg, N);
    k_count  <<<(E + 255) / 256, 256, 0, stream>>>(ei, deg, E);
    k_scan1  <<<B, 256, 0, stream>>>(deg, bsum, N);
    k_scan2  <<<1, 64, 0, stream>>>(bsum, bpre, B);
    k_scan3  <<<B, 256, 0, stream>>>(deg, bpre, indptr, cursor, N);
    k_fill   <<<(E + N + 255) / 256, 256, 0, stream>>>(ei, cursor, csr, E, N);

    // conv1
    gemm_n64<64><<<(N + 63) / 64, 256, 0, stream>>>(x, W1, h1, N, 512);
    k_sc1 <<<(N * 8 + 255) / 256, 256, 0, stream>>>(h1, as1, ad1, sc1s, sc1d, N);
    k_agg1<<<(N + 3) / 4, 256, 0, stream>>>(h1, sc1s, sc1d, indptr, csr, b1, x2, N);

    // conv2
    gemm_n64<64><<<(N + 63) / 64, 256, 0, stream>>>(x2, W2, h2, N, 64);
    k_sc2 <<<(N + 3) / 4, 256, 0, stream>>>(h2, as2, ad2, sc2s, sc2d, N);
    k_agg2<<<(N + 3) / 4, 256, 0, stream>>>(h2, sc2s, sc2d, indptr, csr, b2, out, N);
}

// Round 2
// 811.351 us; speedup vs baseline: 1.1210x; 1.1210x over previous
//
#include <hip/hip_runtime.h>
#include <cstdint>
#include <cstddef>

// Problem constants (from reference): IN=512, H=8, C=8, HID=64, OUT=64
#define LEAKY 0.2f
#define NEG_INF -3.402823466e38f
static const int CHUNK = 2048;   // scan chunk per block (256 thr * 8)

__device__ __forceinline__ float dot4(float4 a, float4 b) {
    return a.x * b.x + a.y * b.y + a.z * b.z + a.w * b.w;
}

// ---------------------------------------------------------------- CSR build
__global__ __launch_bounds__(256) void k_init_deg(int* __restrict__ deg, int Nn) {
    int i = blockIdx.x * 256 + threadIdx.x;
    if (i < Nn) deg[i] = 1;              // self-loop
}

__global__ __launch_bounds__(256) void k_count(const int* __restrict__ ei, int* __restrict__ deg, int E) {
    int e = blockIdx.x * 256 + threadIdx.x;
    if (e < E) atomicAdd(&deg[ei[E + e]], 1);   // ei[1][e] = dst
}

__global__ __launch_bounds__(256) void k_scan1(const int* __restrict__ deg, int* __restrict__ bsum, int Nn) {
    __shared__ int sm[256];
    int b = blockIdx.x, t = threadIdx.x;
    int s = 0;
    int i0 = b * CHUNK + t * 8;
#pragma unroll
    for (int j = 0; j < 8; ++j) { int i = i0 + j; if (i < Nn) s += deg[i]; }
    sm[t] = s;
    __syncthreads();
    for (int o = 128; o; o >>= 1) { if (t < o) sm[t] += sm[t + o]; __syncthreads(); }
    if (t == 0) bsum[b] = sm[0];
}

__global__ void k_scan2(const int* __restrict__ bsum, int* __restrict__ bpre, int B) {
    int l = threadIdx.x;            // 64 threads, B <= 64
    int v = (l < B) ? bsum[l] : 0;
    int inc = v;
#pragma unroll
    for (int o = 1; o < 64; o <<= 1) { int u = __shfl_up(inc, o); if (l >= o) inc += u; }
    if (l < B) bpre[l] = inc - v;   // exclusive
}

__global__ __launch_bounds__(256) void k_scan3(const int* __restrict__ deg, const int* __restrict__ bpre,
                                               int* __restrict__ indptr, int* __restrict__ cursor, int Nn) {
    __shared__ int wsum[4];
    int b = blockIdx.x, t = threadIdx.x, lane = t & 63, w = t >> 6;
    int i0 = b * CHUNK + t * 8;
    int d[8]; int s = 0;
#pragma unroll
    for (int j = 0; j < 8; ++j) { int i = i0 + j; d[j] = (i < Nn) ? deg[i] : 0; s += d[j]; }
    int inc = s;
#pragma unroll
    for (int o = 1; o < 64; o <<= 1) { int u = __shfl_up(inc, o); if (lane >= o) inc += u; }
    if (lane == 63) wsum[w] = inc;
    __syncthreads();
    int wofs = 0;
    for (int k = 0; k < w; ++k) wofs += wsum[k];
    int base = bpre[b] + wofs + (inc - s);
    int run = 0;
#pragma unroll
    for (int j = 0; j < 8; ++j) {
        int i = i0 + j;
        if (i < Nn) {
            int v = base + run;
            indptr[i] = v; cursor[i] = v;
            run += d[j];
            if (i == Nn - 1) indptr[Nn] = v + d[j];
        }
    }
}

__global__ __launch_bounds__(256) void k_fill(const int* __restrict__ ei, int* __restrict__ cursor,
                                              int* __restrict__ csr, int E, int Nn) {
    int idx = blockIdx.x * 256 + threadIdx.x;
    if (idx >= E + Nn) return;
    int s, d;
    if (idx < E) { s = ei[idx]; d = ei[E + idx]; }
    else         { s = idx - E; d = s; }
    int slot = atomicAdd(&cursor[d], 1);
    csr[slot] = s;
}

// ---------------------------------------------------------------- SGEMM C[M,64] = A[M,K] @ B[K,64]
template <int KB>
__global__ __launch_bounds__(256) void gemm_n64(const float* __restrict__ A, const float* __restrict__ B,
                                                float* __restrict__ C, int M, int K) {
    __shared__ float As[KB][68];   // transposed: As[kk][r], pad 68 keeps 16B align
    __shared__ float Bs[KB][68];   // Bs[kk][c]
    int tid = threadIdx.x;
    int row0 = blockIdx.x * 64;
    int tx = tid & 15, ty = tid >> 4;
    float acc[4][4] = {};
    for (int k0 = 0; k0 < K; k0 += KB) {
#pragma unroll
        for (int j = 0; j < (64 * KB) / (256 * 4); ++j) {
            int f = tid + 256 * j;
            int r = f / (KB / 4);
            int c4 = f % (KB / 4);
            int rg = row0 + r; if (rg >= M) rg = M - 1;
            float4 v = *(const float4*)(A + (size_t)rg * K + k0 + c4 * 4);
            As[c4 * 4 + 0][r] = v.x; As[c4 * 4 + 1][r] = v.y;
            As[c4 * 4 + 2][r] = v.z; As[c4 * 4 + 3][r] = v.w;
        }
#pragma unroll
        for (int j = 0; j < (KB * 64) / (256 * 4); ++j) {
            int f = tid + 256 * j;
            int kk = f / 16, c4 = f % 16;
            *(float4*)&Bs[kk][c4 * 4] = *(const float4*)(B + (size_t)(k0 + kk) * 64 + c4 * 4);
        }
        __syncthreads();
#pragma unroll
        for (int kk = 0; kk < KB; ++kk) {
            float4 a = *(const float4*)&As[kk][ty * 4];
            float4 b = *(const float4*)&Bs[kk][tx * 4];
            float av[4] = {a.x, a.y, a.z, a.w};
            float bv[4] = {b.x, b.y, b.z, b.w};
#pragma unroll
            for (int i = 0; i < 4; ++i)
#pragma unroll
                for (int j = 0; j < 4; ++j) acc[i][j] += av[i] * bv[j];
        }
        __syncthreads();
    }
#pragma unroll
    for (int i = 0; i < 4; ++i) {
        int rg = row0 + ty * 4 + i;
        if (rg < M) {
            float4 v = make_float4(acc[i][0], acc[i][1], acc[i][2], acc[i][3]);
            *(float4*)(C + (size_t)rg * 64 + tx * 4) = v;
        }
    }
}

// ---------------------------------------------------------------- attention half-scores
__global__ __launch_bounds__(256) void k_sc1(const float* __restrict__ h1, const float* __restrict__ as1,
                                             const float* __restrict__ ad1, float* __restrict__ scs,
                                             float* __restrict__ scd, int Nn) {
    int i = blockIdx.x * 256 + threadIdx.x;   // i = node*8 + head
    if (i >= Nn * 8) return;
    int h = i & 7;
    const float4* hp = (const float4*)(h1 + (size_t)i * 8);   // node*64 + h*8
    float4 v0 = hp[0], v1 = hp[1];
    const float4* asp = (const float4*)(as1 + h * 8);
    const float4* adp = (const float4*)(ad1 + h * 8);
    scs[i] = dot4(v0, asp[0]) + dot4(v1, asp[1]);
    scd[i] = dot4(v0, adp[0]) + dot4(v1, adp[1]);
}

__global__ __launch_bounds__(256) void k_sc2(const float* __restrict__ h2, const float* __restrict__ as2,
                                             const float* __restrict__ ad2, float* __restrict__ scs,
                                             float* __restrict__ scd, int Nn) {
    int wave = (blockIdx.x * 256 + threadIdx.x) >> 6;
    int lane = threadIdx.x & 63;
    if (wave >= Nn) return;
    float v = h2[(size_t)wave * 64 + lane];
    float ss = v * as2[lane], sd = v * ad2[lane];
#pragma unroll
    for (int o = 32; o; o >>= 1) { ss += __shfl_xor(ss, o); sd += __shfl_xor(sd, o); }
    if (lane == 0) { scs[wave] = ss; scd[wave] = sd; }
}

// ---------------------------------------------------------------- conv1 aggregation (8 heads x 8 ch) -> elu -> x2
// One wave per node. Lane l: pass A uses (slot=grp, head=h8); output lane = head (l>>3), channel (l&7).
__global__ __launch_bounds__(256) void k_agg1(const float* __restrict__ h1, const float* __restrict__ scs,
                                              const float* __restrict__ scd, const int* __restrict__ indptr,
                                              const int* __restrict__ csr, const float* __restrict__ b1,
                                              float* __restrict__ x2, int Nn) {
    int node = (blockIdx.x * 256 + threadIdx.x) >> 6;
    int l = threadIdx.x & 63;
    if (node >= Nn) return;
    int h8 = l & 7, grp = l >> 3;
    int start = indptr[node], end = indptr[node + 1];
    float sd = scd[node * 8 + h8];

    // pass 1: per-head max, 8 slots per iteration (lane-parallel)
    float mx = NEG_INF;
    for (int base = start; base < end; base += 8) {
        int slot = base + grp;
        int s = csr[slot < end ? slot : start];
        float v = scs[s * 8 + h8] + sd;
        v = v > 0.f ? v : LEAKY * v;
        mx = fmaxf(mx, (slot < end) ? v : NEG_INF);
    }
#pragma unroll
    for (int o = 8; o < 64; o <<= 1) mx = fmaxf(mx, __shfl_xor(mx, o));
    // now lane l holds max for head h8 = l&7

    // pass 2: dsum lane-parallel; acc serial with minimal per-edge body
    float dsum = 0.f, acc = 0.f;
    for (int base = start; base < end; base += 64) {
        int e = base + l;
        int s64 = csr[e < end ? e : start];         // coalesced batch of up to 64 edge sources
        int nb = min(8, (end - base + 7) >> 3);
        for (int b = 0; b < nb; ++b) {
            int slot = base + b * 8 + grp;
            int sb = __shfl(s64, b * 8 + grp);
            float v = scs[sb * 8 + h8] + sd;
            v = v > 0.f ? v : LEAKY * v;
            float ex = (slot < end) ? __expf(v - mx) : 0.f;
            dsum += ex;
#pragma unroll
            for (int j = 0; j < 8; ++j) {
                float exv = __shfl(ex, (j << 3) | grp);         // ex of edge j, head grp
                int s = __shfl(s64, b * 8 + j);
                acc += exv * h1[(size_t)s * 64 + l];
            }
        }
    }
#pragma unroll
    for (int o = 8; o < 64; o <<= 1) dsum += __shfl_xor(dsum, o);
    float dsum_out = __shfl(dsum, grp);             // dsum for head grp

    float o1 = acc / (dsum_out + 1e-16f) + b1[l];
    o1 = o1 > 0.f ? o1 : expm1f(o1);                // elu
    x2[(size_t)node * 64 + l] = o1;
}

// ---------------------------------------------------------------- conv2 aggregation (1 head) -> log_softmax -> out
__global__ __launch_bounds__(256) void k_agg2(const float* __restrict__ h2, const float* __restrict__ scs,
                                              const float* __restrict__ scd, const int* __restrict__ indptr,
                                              const int* __restrict__ csr, const float* __restrict__ b2,
                                              float* __restrict__ out, int Nn) {
    int node = (blockIdx.x * 256 + threadIdx.x) >> 6;
    int l = threadIdx.x & 63;
    if (node >= Nn) return;
    int start = indptr[node], end = indptr[node + 1];
    float sd = scd[node];

    // pass 1: max, 64 slots per iteration
    float mx = NEG_INF;
    for (int base = start; base < end; base += 64) {
        int e = base + l;
        int s = csr[e < end ? e : start];
        float v = scs[s] + sd;
        v = v > 0.f ? v : LEAKY * v;
        mx = fmaxf(mx, (e < end) ? v : NEG_INF);
    }
#pragma unroll
    for (int o = 32; o; o >>= 1) mx = fmaxf(mx, __shfl_xor(mx, o));

    // pass 2: ex + dsum lane-parallel; serial body = 2 shfl + load + fma
    float dsum = 0.f, acc = 0.f;
    for (int base = start; base < end; base += 64) {
        int e = base + l;
        int s64 = csr[e < end ? e : start];
        float v = scs[s64] + sd;
        v = v > 0.f ? v : LEAKY * v;
        float ex = (e < end) ? __expf(v - mx) : 0.f;
        dsum += ex;
        int cnt = min(64, end - base);
#pragma unroll 8
        for (int j = 0; j < cnt; ++j) {
            float exv = __shfl(ex, j);
            int s = __shfl(s64, j);
            acc += exv * h2[(size_t)s * 64 + l];
        }
    }
#pragma unroll
    for (int o = 32; o; o >>= 1) dsum += __shfl_xor(dsum, o);

    float o2 = acc / (dsum + 1e-16f) + b2[l];

    // log_softmax over 64 lanes
    float m2 = o2;
#pragma unroll
    for (int d = 32; d; d >>= 1) m2 = fmaxf(m2, __shfl_xor(m2, d));
    float e = __expf(o2 - m2);
    float se = e;
#pragma unroll
    for (int d = 32; d; d >>= 1) se += __shfl_xor(se, d);
    out[(size_t)node * 64 + l] = o2 - m2 - __logf(se);
}

// ---------------------------------------------------------------- launch
extern "C" void kernel_launch(void* const* d_in, const int* in_sizes, int n_in,
                              void* d_out, int out_size, void* d_ws, size_t ws_size,
                              hipStream_t stream) {
    (void)n_in; (void)out_size; (void)ws_size;
    const float* x   = (const float*)d_in[0];
    const int*   ei  = (const int*)d_in[1];
    const float* W1  = (const float*)d_in[2];
    const float* as1 = (const float*)d_in[3];
    const float* ad1 = (const float*)d_in[4];
    const float* b1  = (const float*)d_in[5];
    const float* W2  = (const float*)d_in[6];
    const float* as2 = (const float*)d_in[7];
    const float* ad2 = (const float*)d_in[8];
    const float* b2  = (const float*)d_in[9];
    float* out = (float*)d_out;

    const int N = in_sizes[0] / 512;
    const int E = in_sizes[1] / 2;

    char* p = (char*)d_ws;
    auto alloc = [&](size_t bytes) -> char* {
        char* r = p; p += (bytes + 255) & ~(size_t)255; return r;
    };
    float* h1    = (float*)alloc((size_t)N * 64 * 4);
    float* x2    = (float*)alloc((size_t)N * 64 * 4);
    float* h2    = h1;                 // overlay: h1 dead after k_agg1
    float* sc1s  = (float*)alloc((size_t)N * 8 * 4);
    float* sc1d  = (float*)alloc((size_t)N * 8 * 4);
    float* sc2s  = (float*)alloc((size_t)N * 4);
    float* sc2d  = (float*)alloc((size_t)N * 4);
    int*   deg   = (int*)alloc((size_t)N * 4);
    int*   cursor= (int*)alloc((size_t)N * 4);
    int*   indptr= (int*)alloc((size_t)(N + 1) * 4);
    int*   csr   = (int*)alloc((size_t)(E + N) * 4);
    int*   bsum  = (int*)alloc(64 * 4);
    int*   bpre  = (int*)alloc(64 * 4);

    const int B = (N + CHUNK - 1) / CHUNK;     // 49 <= 64

    // CSR build
    k_init_deg<<<(N + 255) / 256, 256, 0, stream>>>(deg, N);
    k_count  <<<(E + 255) / 256, 256, 0, stream>>>(ei, deg, E);
    k_scan1  <<<B, 256, 0, stream>>>(deg, bsum, N);
    k_scan2  <<<1, 64, 0, stream>>>(bsum, bpre, B);
    k_scan3  <<<B, 256, 0, stream>>>(deg, bpre, indptr, cursor, N);
    k_fill   <<<(E + N + 255) / 256, 256, 0, stream>>>(ei, cursor, csr, E, N);

    // conv1
    gemm_n64<64><<<(N + 63) / 64, 256, 0, stream>>>(x, W1, h1, N, 512);
    k_sc1 <<<(N * 8 + 255) / 256, 256, 0, stream>>>(h1, as1, ad1, sc1s, sc1d, N);
    k_agg1<<<(N + 3) / 4, 256, 0, stream>>>(h1, sc1s, sc1d, indptr, csr, b1, x2, N);

    // conv2
    gemm_n64<64><<<(N + 63) / 64, 256, 0, stream>>>(x2, W2, h2, N, 64);
    k_sc2 <<<(N + 3) / 4, 256, 0, stream>>>(h2, as2, ad2, sc2s, sc2d, N);
    k_agg2<<<(N + 3) / 4, 256, 0, stream>>>(h2, sc2s, sc2d, indptr, csr, b2, out, N);
}

// Round 3
// 742.306 us; speedup vs baseline: 1.2253x; 1.0930x over previous
//
#include <hip/hip_runtime.h>
#include <cstdint>
#include <cstddef>

// Problem constants (from reference): IN=512, H=8, C=8, HID=64, OUT=64
#define LEAKY 0.2f
#define NEG_INF -3.402823466e38f
static const int CHUNK = 2048;   // scan chunk per block (256 thr * 8)

__device__ __forceinline__ float dot4(float4 a, float4 b) {
    return a.x * b.x + a.y * b.y + a.z * b.z + a.w * b.w;
}

// ---------------------------------------------------------------- CSR build
__global__ __launch_bounds__(256) void k_init_deg(int* __restrict__ deg, int Nn) {
    int i = blockIdx.x * 256 + threadIdx.x;
    if (i < Nn) deg[i] = 1;              // self-loop
}

// XCD-partitioned count: partition p (= blockIdx&7) owns dst in [lo,hi).
// With blockIdx%8 -> XCD round-robin, deg[lo:hi) is written by one XCD only,
// so atomics/lines stay local to that XCD's L2.
__global__ __launch_bounds__(256) void k_count_p(const int* __restrict__ ei, int* __restrict__ deg,
                                                 int E, int Nn) {
    int part = blockIdx.x & 7;
    int lo = (int)((long long)Nn * part >> 3);
    int hi = (int)((long long)Nn * (part + 1) >> 3);
    int nthr = (gridDim.x >> 3) * 256;
    int tid = (blockIdx.x >> 3) * 256 + threadIdx.x;
    for (int e = tid; e < E; e += nthr) {
        int d = ei[E + e];
        if (d >= lo && d < hi) atomicAdd(&deg[d], 1);
    }
}

__global__ __launch_bounds__(256) void k_scan1(const int* __restrict__ deg, int* __restrict__ bsum, int Nn) {
    __shared__ int sm[256];
    int b = blockIdx.x, t = threadIdx.x;
    int s = 0;
    int i0 = b * CHUNK + t * 8;
#pragma unroll
    for (int j = 0; j < 8; ++j) { int i = i0 + j; if (i < Nn) s += deg[i]; }
    sm[t] = s;
    __syncthreads();
    for (int o = 128; o; o >>= 1) { if (t < o) sm[t] += sm[t + o]; __syncthreads(); }
    if (t == 0) bsum[b] = sm[0];
}

__global__ void k_scan2(const int* __restrict__ bsum, int* __restrict__ bpre, int B) {
    int l = threadIdx.x;            // 64 threads, B <= 64
    int v = (l < B) ? bsum[l] : 0;
    int inc = v;
#pragma unroll
    for (int o = 1; o < 64; o <<= 1) { int u = __shfl_up(inc, o); if (l >= o) inc += u; }
    if (l < B) bpre[l] = inc - v;   // exclusive
}

__global__ __launch_bounds__(256) void k_scan3(const int* __restrict__ deg, const int* __restrict__ bpre,
                                               int* __restrict__ indptr, int* __restrict__ cursor, int Nn) {
    __shared__ int wsum[4];
    int b = blockIdx.x, t = threadIdx.x, lane = t & 63, w = t >> 6;
    int i0 = b * CHUNK + t * 8;
    int d[8]; int s = 0;
#pragma unroll
    for (int j = 0; j < 8; ++j) { int i = i0 + j; d[j] = (i < Nn) ? deg[i] : 0; s += d[j]; }
    int inc = s;
#pragma unroll
    for (int o = 1; o < 64; o <<= 1) { int u = __shfl_up(inc, o); if (lane >= o) inc += u; }
    if (lane == 63) wsum[w] = inc;
    __syncthreads();
    int wofs = 0;
    for (int k = 0; k < w; ++k) wofs += wsum[k];
    int base = bpre[b] + wofs + (inc - s);
    int run = 0;
#pragma unroll
    for (int j = 0; j < 8; ++j) {
        int i = i0 + j;
        if (i < Nn) {
            int v = base + run;
            indptr[i] = v; cursor[i] = v;
            run += d[j];
            if (i == Nn - 1) indptr[Nn] = v + d[j];
        }
    }
}

// XCD-partitioned fill: same partitioning as k_count_p. csr slots for dst in
// [lo,hi) are contiguous (CSR order), so partition p's stores hit a ~0.85 MB
// region owned by one XCD -> full-line accumulation in its L2 instead of
// 64B-granule HBM writebacks per 4B store.
__global__ __launch_bounds__(256) void k_fill_p(const int* __restrict__ ei, int* __restrict__ cursor,
                                                int* __restrict__ csr, int E, int Nn) {
    int part = blockIdx.x & 7;
    int lo = (int)((long long)Nn * part >> 3);
    int hi = (int)((long long)Nn * (part + 1) >> 3);
    int nthr = (gridDim.x >> 3) * 256;
    int tid = (blockIdx.x >> 3) * 256 + threadIdx.x;
    int tot = E + Nn;
    for (int idx = tid; idx < tot; idx += nthr) {
        int d = (idx < E) ? ei[E + idx] : idx - E;
        if (d >= lo && d < hi) {
            int s = (idx < E) ? ei[idx] : idx - E;
            int slot = atomicAdd(&cursor[d], 1);
            csr[slot] = s;
        }
    }
}

// ---------------------------------------------------------------- SGEMM C[M,64] = A[M,K] @ B[K,64]
template <int KB>
__global__ __launch_bounds__(256) void gemm_n64(const float* __restrict__ A, const float* __restrict__ B,
                                                float* __restrict__ C, int M, int K) {
    __shared__ float As[KB][68];   // transposed: As[kk][r], pad 68 keeps 16B align
    __shared__ float Bs[KB][68];   // Bs[kk][c]
    int tid = threadIdx.x;
    int row0 = blockIdx.x * 64;
    int tx = tid & 15, ty = tid >> 4;
    float acc[4][4] = {};
    for (int k0 = 0; k0 < K; k0 += KB) {
#pragma unroll
        for (int j = 0; j < (64 * KB) / (256 * 4); ++j) {
            int f = tid + 256 * j;
            int r = f / (KB / 4);
            int c4 = f % (KB / 4);
            int rg = row0 + r; if (rg >= M) rg = M - 1;
            float4 v = *(const float4*)(A + (size_t)rg * K + k0 + c4 * 4);
            As[c4 * 4 + 0][r] = v.x; As[c4 * 4 + 1][r] = v.y;
            As[c4 * 4 + 2][r] = v.z; As[c4 * 4 + 3][r] = v.w;
        }
#pragma unroll
        for (int j = 0; j < (KB * 64) / (256 * 4); ++j) {
            int f = tid + 256 * j;
            int kk = f / 16, c4 = f % 16;
            *(float4*)&Bs[kk][c4 * 4] = *(const float4*)(B + (size_t)(k0 + kk) * 64 + c4 * 4);
        }
        __syncthreads();
#pragma unroll
        for (int kk = 0; kk < KB; ++kk) {
            float4 a = *(const float4*)&As[kk][ty * 4];
            float4 b = *(const float4*)&Bs[kk][tx * 4];
            float av[4] = {a.x, a.y, a.z, a.w};
            float bv[4] = {b.x, b.y, b.z, b.w};
#pragma unroll
            for (int i = 0; i < 4; ++i)
#pragma unroll
                for (int j = 0; j < 4; ++j) acc[i][j] += av[i] * bv[j];
        }
        __syncthreads();
    }
#pragma unroll
    for (int i = 0; i < 4; ++i) {
        int rg = row0 + ty * 4 + i;
        if (rg < M) {
            float4 v = make_float4(acc[i][0], acc[i][1], acc[i][2], acc[i][3]);
            *(float4*)(C + (size_t)rg * 64 + tx * 4) = v;
        }
    }
}

// ---------------------------------------------------------------- attention half-scores
__global__ __launch_bounds__(256) void k_sc1(const float* __restrict__ h1, const float* __restrict__ as1,
                                             const float* __restrict__ ad1, float* __restrict__ scs,
                                             float* __restrict__ scd, int Nn) {
    int i = blockIdx.x * 256 + threadIdx.x;   // i = node*8 + head
    if (i >= Nn * 8) return;
    int h = i & 7;
    const float4* hp = (const float4*)(h1 + (size_t)i * 8);   // node*64 + h*8
    float4 v0 = hp[0], v1 = hp[1];
    const float4* asp = (const float4*)(as1 + h * 8);
    const float4* adp = (const float4*)(ad1 + h * 8);
    scs[i] = dot4(v0, asp[0]) + dot4(v1, asp[1]);
    scd[i] = dot4(v0, adp[0]) + dot4(v1, adp[1]);
}

__global__ __launch_bounds__(256) void k_sc2(const float* __restrict__ h2, const float* __restrict__ as2,
                                             const float* __restrict__ ad2, float* __restrict__ scs,
                                             float* __restrict__ scd, int Nn) {
    int wave = (blockIdx.x * 256 + threadIdx.x) >> 6;
    int lane = threadIdx.x & 63;
    if (wave >= Nn) return;
    float v = h2[(size_t)wave * 64 + lane];
    float ss = v * as2[lane], sd = v * ad2[lane];
#pragma unroll
    for (int o = 32; o; o >>= 1) { ss += __shfl_xor(ss, o); sd += __shfl_xor(sd, o); }
    if (lane == 0) { scs[wave] = ss; scd[wave] = sd; }
}

// ---------------------------------------------------------------- conv1 aggregation (8 heads x 8 ch) -> elu -> x2
__global__ __launch_bounds__(256) void k_agg1(const float* __restrict__ h1, const float* __restrict__ scs,
                                              const float* __restrict__ scd, const int* __restrict__ indptr,
                                              const int* __restrict__ csr, const float* __restrict__ b1,
                                              float* __restrict__ x2, int Nn) {
    int node = (blockIdx.x * 256 + threadIdx.x) >> 6;
    int l = threadIdx.x & 63;
    if (node >= Nn) return;
    int h8 = l & 7, grp = l >> 3;
    int start = indptr[node], end = indptr[node + 1];
    float sd = scd[node * 8 + h8];

    // pass 1: per-head max, 8 slots per iteration (lane-parallel)
    float mx = NEG_INF;
    for (int base = start; base < end; base += 8) {
        int slot = base + grp;
        int s = csr[slot < end ? slot : start];
        float v = scs[s * 8 + h8] + sd;
        v = v > 0.f ? v : LEAKY * v;
        mx = fmaxf(mx, (slot < end) ? v : NEG_INF);
    }
#pragma unroll
    for (int o = 8; o < 64; o <<= 1) mx = fmaxf(mx, __shfl_xor(mx, o));
    // now lane l holds max for head h8 = l&7

    // pass 2: dsum lane-parallel; acc serial with minimal per-edge body
    float dsum = 0.f, acc = 0.f;
    for (int base = start; base < end; base += 64) {
        int e = base + l;
        int s64 = csr[e < end ? e : start];         // coalesced batch of up to 64 edge sources
        int nb = min(8, (end - base + 7) >> 3);
        for (int b = 0; b < nb; ++b) {
            int slot = base + b * 8 + grp;
            int sb = __shfl(s64, b * 8 + grp);
            float v = scs[sb * 8 + h8] + sd;
            v = v > 0.f ? v : LEAKY * v;
            float ex = (slot < end) ? __expf(v - mx) : 0.f;
            dsum += ex;
#pragma unroll
            for (int j = 0; j < 8; ++j) {
                float exv = __shfl(ex, (j << 3) | grp);         // ex of edge j, head grp
                int s = __shfl(s64, b * 8 + j);
                acc += exv * h1[(size_t)s * 64 + l];
            }
        }
    }
#pragma unroll
    for (int o = 8; o < 64; o <<= 1) dsum += __shfl_xor(dsum, o);
    float dsum_out = __shfl(dsum, grp);             // dsum for head grp

    float o1 = acc / (dsum_out + 1e-16f) + b1[l];
    o1 = o1 > 0.f ? o1 : expm1f(o1);                // elu
    x2[(size_t)node * 64 + l] = o1;
}

// ---------------------------------------------------------------- conv2 aggregation (1 head) -> log_softmax -> out
__global__ __launch_bounds__(256) void k_agg2(const float* __restrict__ h2, const float* __restrict__ scs,
                                              const float* __restrict__ scd, const int* __restrict__ indptr,
                                              const int* __restrict__ csr, const float* __restrict__ b2,
                                              float* __restrict__ out, int Nn) {
    int node = (blockIdx.x * 256 + threadIdx.x) >> 6;
    int l = threadIdx.x & 63;
    if (node >= Nn) return;
    int start = indptr[node], end = indptr[node + 1];
    float sd = scd[node];

    // pass 1: max, 64 slots per iteration
    float mx = NEG_INF;
    for (int base = start; base < end; base += 64) {
        int e = base + l;
        int s = csr[e < end ? e : start];
        float v = scs[s] + sd;
        v = v > 0.f ? v : LEAKY * v;
        mx = fmaxf(mx, (e < end) ? v : NEG_INF);
    }
#pragma unroll
    for (int o = 32; o; o >>= 1) mx = fmaxf(mx, __shfl_xor(mx, o));

    // pass 2: ex + dsum lane-parallel; serial body = 2 shfl + load + fma
    float dsum = 0.f, acc = 0.f;
    for (int base = start; base < end; base += 64) {
        int e = base + l;
        int s64 = csr[e < end ? e : start];
        float v = scs[s64] + sd;
        v = v > 0.f ? v : LEAKY * v;
        float ex = (e < end) ? __expf(v - mx) : 0.f;
        dsum += ex;
        int cnt = min(64, end - base);
#pragma unroll 8
        for (int j = 0; j < cnt; ++j) {
            float exv = __shfl(ex, j);
            int s = __shfl(s64, j);
            acc += exv * h2[(size_t)s * 64 + l];
        }
    }
#pragma unroll
    for (int o = 32; o; o >>= 1) dsum += __shfl_xor(dsum, o);

    float o2 = acc / (dsum + 1e-16f) + b2[l];

    // log_softmax over 64 lanes
    float m2 = o2;
#pragma unroll
    for (int d = 32; d; d >>= 1) m2 = fmaxf(m2, __shfl_xor(m2, d));
    float e = __expf(o2 - m2);
    float se = e;
#pragma unroll
    for (int d = 32; d; d >>= 1) se += __shfl_xor(se, d);
    out[(size_t)node * 64 + l] = o2 - m2 - __logf(se);
}

// ---------------------------------------------------------------- launch
extern "C" void kernel_launch(void* const* d_in, const int* in_sizes, int n_in,
                              void* d_out, int out_size, void* d_ws, size_t ws_size,
                              hipStream_t stream) {
    (void)n_in; (void)out_size; (void)ws_size;
    const float* x   = (const float*)d_in[0];
    const int*   ei  = (const int*)d_in[1];
    const float* W1  = (const float*)d_in[2];
    const float* as1 = (const float*)d_in[3];
    const float* ad1 = (const float*)d_in[4];
    const float* b1  = (const float*)d_in[5];
    const float* W2  = (const float*)d_in[6];
    const float* as2 = (const float*)d_in[7];
    const float* ad2 = (const float*)d_in[8];
    const float* b2  = (const float*)d_in[9];
    float* out = (float*)d_out;

    const int N = in_sizes[0] / 512;
    const int E = in_sizes[1] / 2;

    char* p = (char*)d_ws;
    auto alloc = [&](size_t bytes) -> char* {
        char* r = p; p += (bytes + 255) & ~(size_t)255; return r;
    };
    float* h1    = (float*)alloc((size_t)N * 64 * 4);
    float* x2    = (float*)alloc((size_t)N * 64 * 4);
    float* h2    = h1;                 // overlay: h1 dead after k_agg1
    float* sc1s  = (float*)alloc((size_t)N * 8 * 4);
    float* sc1d  = (float*)alloc((size_t)N * 8 * 4);
    float* sc2s  = (float*)alloc((size_t)N * 4);
    float* sc2d  = (float*)alloc((size_t)N * 4);
    int*   deg   = (int*)alloc((size_t)N * 4);
    int*   cursor= (int*)alloc((size_t)N * 4);
    int*   indptr= (int*)alloc((size_t)(N + 1) * 4);
    int*   csr   = (int*)alloc((size_t)(E + N) * 4);
    int*   bsum  = (int*)alloc(64 * 4);
    int*   bpre  = (int*)alloc(64 * 4);

    const int B = (N + CHUNK - 1) / CHUNK;     // 49 <= 64

    // CSR build
    k_init_deg<<<(N + 255) / 256, 256, 0, stream>>>(deg, N);
    k_count_p<<<1024, 256, 0, stream>>>(ei, deg, E, N);
    k_scan1  <<<B, 256, 0, stream>>>(deg, bsum, N);
    k_scan2  <<<1, 64, 0, stream>>>(bsum, bpre, B);
    k_scan3  <<<B, 256, 0, stream>>>(deg, bpre, indptr, cursor, N);
    k_fill_p <<<1024, 256, 0, stream>>>(ei, cursor, csr, E, N);

    // conv1
    gemm_n64<64><<<(N + 63) / 64, 256, 0, stream>>>(x, W1, h1, N, 512);
    k_sc1 <<<(N * 8 + 255) / 256, 256, 0, stream>>>(h1, as1, ad1, sc1s, sc1d, N);
    k_agg1<<<(N + 3) / 4, 256, 0, stream>>>(h1, sc1s, sc1d, indptr, csr, b1, x2, N);

    // conv2
    gemm_n64<64><<<(N + 63) / 64, 256, 0, stream>>>(x2, W2, h2, N, 64);
    k_sc2 <<<(N + 3) / 4, 256, 0, stream>>>(h2, as2, ad2, sc2s, sc2d, N);
    k_agg2<<<(N + 3) / 4, 256, 0, stream>>>(h2, sc2s, sc2d, indptr, csr, b2, out, N);
}

// Round 4
// 723.359 us; speedup vs baseline: 1.2574x; 1.0262x over previous
//
#include <hip/hip_runtime.h>
#include <cstdint>
#include <cstddef>

// Problem constants (from reference): IN=512, H=8, C=8, HID=64, OUT=64
#define LEAKY 0.2f
#define NEG_INF -3.402823466e38f
static const int CHUNK = 2048;   // scan chunk per block (256 thr * 8)

typedef __attribute__((ext_vector_type(8))) short short8;
typedef __attribute__((ext_vector_type(4))) float floatx4;

__device__ __forceinline__ float dot4(float4 a, float4 b) {
    return a.x * b.x + a.y * b.y + a.z * b.z + a.w * b.w;
}

__device__ __forceinline__ unsigned short f2bf(float f) {   // RNE float->bf16
    unsigned u = __float_as_uint(f);
    u += 0x7fffu + ((u >> 16) & 1u);
    return (unsigned short)(u >> 16);
}

// ---------------------------------------------------------------- CSR build
__global__ __launch_bounds__(256) void k_init_deg(int* __restrict__ deg, int Nn) {
    int i = blockIdx.x * 256 + threadIdx.x;
    if (i < Nn) deg[i] = 1;              // self-loop
}

// XCD-partitioned count: partition p (= blockIdx&7) owns dst in [lo,hi).
__global__ __launch_bounds__(256) void k_count_p(const int* __restrict__ ei, int* __restrict__ deg,
                                                 int E, int Nn) {
    int part = blockIdx.x & 7;
    int lo = (int)((long long)Nn * part >> 3);
    int hi = (int)((long long)Nn * (part + 1) >> 3);
    int nthr = (gridDim.x >> 3) * 256;
    int tid = (blockIdx.x >> 3) * 256 + threadIdx.x;
    for (int e = tid; e < E; e += nthr) {
        int d = ei[E + e];
        if (d >= lo && d < hi) atomicAdd(&deg[d], 1);
    }
}

__global__ __launch_bounds__(256) void k_scan1(const int* __restrict__ deg, int* __restrict__ bsum, int Nn) {
    __shared__ int sm[256];
    int b = blockIdx.x, t = threadIdx.x;
    int s = 0;
    int i0 = b * CHUNK + t * 8;
#pragma unroll
    for (int j = 0; j < 8; ++j) { int i = i0 + j; if (i < Nn) s += deg[i]; }
    sm[t] = s;
    __syncthreads();
    for (int o = 128; o; o >>= 1) { if (t < o) sm[t] += sm[t + o]; __syncthreads(); }
    if (t == 0) bsum[b] = sm[0];
}

__global__ void k_scan2(const int* __restrict__ bsum, int* __restrict__ bpre, int B) {
    int l = threadIdx.x;            // 64 threads, B <= 64
    int v = (l < B) ? bsum[l] : 0;
    int inc = v;
#pragma unroll
    for (int o = 1; o < 64; o <<= 1) { int u = __shfl_up(inc, o); if (l >= o) inc += u; }
    if (l < B) bpre[l] = inc - v;   // exclusive
}

__global__ __launch_bounds__(256) void k_scan3(const int* __restrict__ deg, const int* __restrict__ bpre,
                                               int* __restrict__ indptr, int* __restrict__ cursor, int Nn) {
    __shared__ int wsum[4];
    int b = blockIdx.x, t = threadIdx.x, lane = t & 63, w = t >> 6;
    int i0 = b * CHUNK + t * 8;
    int d[8]; int s = 0;
#pragma unroll
    for (int j = 0; j < 8; ++j) { int i = i0 + j; d[j] = (i < Nn) ? deg[i] : 0; s += d[j]; }
    int inc = s;
#pragma unroll
    for (int o = 1; o < 64; o <<= 1) { int u = __shfl_up(inc, o); if (lane >= o) inc += u; }
    if (lane == 63) wsum[w] = inc;
    __syncthreads();
    int wofs = 0;
    for (int k = 0; k < w; ++k) wofs += wsum[k];
    int base = bpre[b] + wofs + (inc - s);
    int run = 0;
#pragma unroll
    for (int j = 0; j < 8; ++j) {
        int i = i0 + j;
        if (i < Nn) {
            int v = base + run;
            indptr[i] = v; cursor[i] = v;
            run += d[j];
            if (i == Nn - 1) indptr[Nn] = v + d[j];
        }
    }
}

// XCD-partitioned fill (see round-2 note): one XCD owns each csr region.
__global__ __launch_bounds__(256) void k_fill_p(const int* __restrict__ ei, int* __restrict__ cursor,
                                                int* __restrict__ csr, int E, int Nn) {
    int part = blockIdx.x & 7;
    int lo = (int)((long long)Nn * part >> 3);
    int hi = (int)((long long)Nn * (part + 1) >> 3);
    int nthr = (gridDim.x >> 3) * 256;
    int tid = (blockIdx.x >> 3) * 256 + threadIdx.x;
    int tot = E + Nn;
    for (int idx = tid; idx < tot; idx += nthr) {
        int d = (idx < E) ? ei[E + idx] : idx - E;
        if (d >= lo && d < hi) {
            int s = (idx < E) ? ei[idx] : idx - E;
            int slot = atomicAdd(&cursor[d], 1);
            csr[slot] = s;
        }
    }
}

// ---------------------------------------------------------------- W1 -> bf16 transposed [64][512]
__global__ __launch_bounds__(256) void k_prepW(const float* __restrict__ W1, unsigned short* __restrict__ W1t) {
    int i = blockIdx.x * 256 + threadIdx.x;      // i over 64*512
    if (i >= 64 * 512) return;
    int n = i >> 9, k = i & 511;
    W1t[i] = f2bf(W1[k * 64 + n]);               // coalesced write, cached read
}

// ---------------------------------------------------------------- MFMA GEMM1: h1[M,64] = x[M,512] @ W1
// 128x64 block tile, 16x16x32 bf16 MFMA, fp32 accumulate. Wave w: rows 32w..32w+31.
__global__ __launch_bounds__(256) void gemm1_mfma(const float* __restrict__ A, const unsigned short* __restrict__ W1t,
                                                  float* __restrict__ C, int M) {
    __shared__ __align__(16) unsigned short As[128][40];   // 80B row stride: 16B-aligned, 2-way banks
    __shared__ __align__(16) unsigned short Bs[64][40];
    int t = threadIdx.x;
    int w = t >> 6, l = t & 63;
    int quad = l >> 4, lm = l & 15;
    int row0 = blockIdx.x * 128;

    floatx4 acc[2][4] = {};

    for (int k0 = 0; k0 < 512; k0 += 32) {
        // stage A: 128 rows x 32 k (fp32 -> bf16)
#pragma unroll
        for (int j = 0; j < 4; ++j) {
            int f = t + 256 * j;
            int r = f >> 3, c4 = f & 7;
            int rg = row0 + r; if (rg >= M) rg = M - 1;
            float4 v = *(const float4*)(A + (size_t)rg * 512 + k0 + c4 * 4);
            ushort4 b; b.x = f2bf(v.x); b.y = f2bf(v.y); b.z = f2bf(v.z); b.w = f2bf(v.w);
            *(ushort4*)&As[r][c4 * 4] = b;
        }
        // stage B: 64 n-rows x 32 k from pre-transposed bf16 W1t
        {
            int n = t >> 2, seg = t & 3;
            *(uint4*)&Bs[n][seg * 8] = *(const uint4*)(W1t + (size_t)n * 512 + k0 + seg * 8);
        }
        __syncthreads();

        short8 af[2], bf[4];
#pragma unroll
        for (int tm = 0; tm < 2; ++tm) {
            int m = w * 32 + tm * 16 + lm;
            af[tm] = *(const short8*)&As[m][quad * 8];
        }
#pragma unroll
        for (int tn = 0; tn < 4; ++tn) {
            int n = tn * 16 + lm;
            bf[tn] = *(const short8*)&Bs[n][quad * 8];
        }
#pragma unroll
        for (int tm = 0; tm < 2; ++tm)
#pragma unroll
            for (int tn = 0; tn < 4; ++tn)
                acc[tm][tn] = __builtin_amdgcn_mfma_f32_16x16x32_bf16(af[tm], bf[tn], acc[tm][tn], 0, 0, 0);
        __syncthreads();
    }

    // epilogue: C/D layout col=lane&15, row=quad*4+reg
#pragma unroll
    for (int tm = 0; tm < 2; ++tm) {
#pragma unroll
        for (int r = 0; r < 4; ++r) {
            int row = row0 + w * 32 + tm * 16 + quad * 4 + r;
            if (row < M) {
#pragma unroll
                for (int tn = 0; tn < 4; ++tn)
                    C[(size_t)row * 64 + tn * 16 + lm] = acc[tm][tn][r];
            }
        }
    }
}

// ---------------------------------------------------------------- SGEMM C[M,64] = A[M,K] @ B[K,64] (fp32, for conv2)
template <int KB>
__global__ __launch_bounds__(256) void gemm_n64(const float* __restrict__ A, const float* __restrict__ B,
                                                float* __restrict__ C, int M, int K) {
    __shared__ float As[KB][68];
    __shared__ float Bs[KB][68];
    int tid = threadIdx.x;
    int row0 = blockIdx.x * 64;
    int tx = tid & 15, ty = tid >> 4;
    float acc[4][4] = {};
    for (int k0 = 0; k0 < K; k0 += KB) {
#pragma unroll
        for (int j = 0; j < (64 * KB) / (256 * 4); ++j) {
            int f = tid + 256 * j;
            int r = f / (KB / 4);
            int c4 = f % (KB / 4);
            int rg = row0 + r; if (rg >= M) rg = M - 1;
            float4 v = *(const float4*)(A + (size_t)rg * K + k0 + c4 * 4);
            As[c4 * 4 + 0][r] = v.x; As[c4 * 4 + 1][r] = v.y;
            As[c4 * 4 + 2][r] = v.z; As[c4 * 4 + 3][r] = v.w;
        }
#pragma unroll
        for (int j = 0; j < (KB * 64) / (256 * 4); ++j) {
            int f = tid + 256 * j;
            int kk = f / 16, c4 = f % 16;
            *(float4*)&Bs[kk][c4 * 4] = *(const float4*)(B + (size_t)(k0 + kk) * 64 + c4 * 4);
        }
        __syncthreads();
#pragma unroll
        for (int kk = 0; kk < KB; ++kk) {
            float4 a = *(const float4*)&As[kk][ty * 4];
            float4 b = *(const float4*)&Bs[kk][tx * 4];
            float av[4] = {a.x, a.y, a.z, a.w};
            float bv[4] = {b.x, b.y, b.z, b.w};
#pragma unroll
            for (int i = 0; i < 4; ++i)
#pragma unroll
                for (int j = 0; j < 4; ++j) acc[i][j] += av[i] * bv[j];
        }
        __syncthreads();
    }
#pragma unroll
    for (int i = 0; i < 4; ++i) {
        int rg = row0 + ty * 4 + i;
        if (rg < M) {
            float4 v = make_float4(acc[i][0], acc[i][1], acc[i][2], acc[i][3]);
            *(float4*)(C + (size_t)rg * 64 + tx * 4) = v;
        }
    }
}

// ---------------------------------------------------------------- attention half-scores
__global__ __launch_bounds__(256) void k_sc1(const float* __restrict__ h1, const float* __restrict__ as1,
                                             const float* __restrict__ ad1, float* __restrict__ scs,
                                             float* __restrict__ scd, int Nn) {
    int i = blockIdx.x * 256 + threadIdx.x;   // i = node*8 + head
    if (i >= Nn * 8) return;
    int h = i & 7;
    const float4* hp = (const float4*)(h1 + (size_t)i * 8);   // node*64 + h*8
    float4 v0 = hp[0], v1 = hp[1];
    const float4* asp = (const float4*)(as1 + h * 8);
    const float4* adp = (const float4*)(ad1 + h * 8);
    scs[i] = dot4(v0, asp[0]) + dot4(v1, asp[1]);
    scd[i] = dot4(v0, adp[0]) + dot4(v1, adp[1]);
}

__global__ __launch_bounds__(256) void k_sc2(const float* __restrict__ h2, const float* __restrict__ as2,
                                             const float* __restrict__ ad2, float* __restrict__ scs,
                                             float* __restrict__ scd, int Nn) {
    int wave = (blockIdx.x * 256 + threadIdx.x) >> 6;
    int lane = threadIdx.x & 63;
    if (wave >= Nn) return;
    float v = h2[(size_t)wave * 64 + lane];
    float ss = v * as2[lane], sd = v * ad2[lane];
#pragma unroll
    for (int o = 32; o; o >>= 1) { ss += __shfl_xor(ss, o); sd += __shfl_xor(sd, o); }
    if (lane == 0) { scs[wave] = ss; scd[wave] = sd; }
}

// ---------------------------------------------------------------- conv1 aggregation (8 heads x 8 ch) -> elu -> x2
__global__ __launch_bounds__(256) void k_agg1(const float* __restrict__ h1, const float* __restrict__ scs,
                                              const float* __restrict__ scd, const int* __restrict__ indptr,
                                              const int* __restrict__ csr, const float* __restrict__ b1,
                                              float* __restrict__ x2, int Nn) {
    int node = (blockIdx.x * 256 + threadIdx.x) >> 6;
    int l = threadIdx.x & 63;
    if (node >= Nn) return;
    int h8 = l & 7, grp = l >> 3;
    int start = indptr[node], end = indptr[node + 1];
    float sd = scd[node * 8 + h8];

    // pass 1: per-head max, 8 slots per iteration (lane-parallel)
    float mx = NEG_INF;
    for (int base = start; base < end; base += 8) {
        int slot = base + grp;
        int s = csr[slot < end ? slot : start];
        float v = scs[s * 8 + h8] + sd;
        v = v > 0.f ? v : LEAKY * v;
        mx = fmaxf(mx, (slot < end) ? v : NEG_INF);
    }
#pragma unroll
    for (int o = 8; o < 64; o <<= 1) mx = fmaxf(mx, __shfl_xor(mx, o));

    // pass 2: dsum lane-parallel; acc serial with minimal per-edge body
    float dsum = 0.f, acc = 0.f;
    for (int base = start; base < end; base += 64) {
        int e = base + l;
        int s64 = csr[e < end ? e : start];
        int nb = min(8, (end - base + 7) >> 3);
        for (int b = 0; b < nb; ++b) {
            int slot = base + b * 8 + grp;
            int sb = __shfl(s64, b * 8 + grp);
            float v = scs[sb * 8 + h8] + sd;
            v = v > 0.f ? v : LEAKY * v;
            float ex = (slot < end) ? __expf(v - mx) : 0.f;
            dsum += ex;
#pragma unroll
            for (int j = 0; j < 8; ++j) {
                float exv = __shfl(ex, (j << 3) | grp);
                int s = __shfl(s64, b * 8 + j);
                acc += exv * h1[(size_t)s * 64 + l];
            }
        }
    }
#pragma unroll
    for (int o = 8; o < 64; o <<= 1) dsum += __shfl_xor(dsum, o);
    float dsum_out = __shfl(dsum, grp);

    float o1 = acc / (dsum_out + 1e-16f) + b1[l];
    o1 = o1 > 0.f ? o1 : expm1f(o1);                // elu
    x2[(size_t)node * 64 + l] = o1;
}

// ---------------------------------------------------------------- conv2 aggregation (1 head) -> log_softmax -> out
__global__ __launch_bounds__(256) void k_agg2(const float* __restrict__ h2, const float* __restrict__ scs,
                                              const float* __restrict__ scd, const int* __restrict__ indptr,
                                              const int* __restrict__ csr, const float* __restrict__ b2,
                                              float* __restrict__ out, int Nn) {
    int node = (blockIdx.x * 256 + threadIdx.x) >> 6;
    int l = threadIdx.x & 63;
    if (node >= Nn) return;
    int start = indptr[node], end = indptr[node + 1];
    float sd = scd[node];

    float mx = NEG_INF;
    for (int base = start; base < end; base += 64) {
        int e = base + l;
        int s = csr[e < end ? e : start];
        float v = scs[s] + sd;
        v = v > 0.f ? v : LEAKY * v;
        mx = fmaxf(mx, (e < end) ? v : NEG_INF);
    }
#pragma unroll
    for (int o = 32; o; o >>= 1) mx = fmaxf(mx, __shfl_xor(mx, o));

    float dsum = 0.f, acc = 0.f;
    for (int base = start; base < end; base += 64) {
        int e = base + l;
        int s64 = csr[e < end ? e : start];
        float v = scs[s64] + sd;
        v = v > 0.f ? v : LEAKY * v;
        float ex = (e < end) ? __expf(v - mx) : 0.f;
        dsum += ex;
        int cnt = min(64, end - base);
#pragma unroll 8
        for (int j = 0; j < cnt; ++j) {
            float exv = __shfl(ex, j);
            int s = __shfl(s64, j);
            acc += exv * h2[(size_t)s * 64 + l];
        }
    }
#pragma unroll
    for (int o = 32; o; o >>= 1) dsum += __shfl_xor(dsum, o);

    float o2 = acc / (dsum + 1e-16f) + b2[l];

    float m2 = o2;
#pragma unroll
    for (int d = 32; d; d >>= 1) m2 = fmaxf(m2, __shfl_xor(m2, d));
    float e = __expf(o2 - m2);
    float se = e;
#pragma unroll
    for (int d = 32; d; d >>= 1) se += __shfl_xor(se, d);
    out[(size_t)node * 64 + l] = o2 - m2 - __logf(se);
}

// ---------------------------------------------------------------- launch
extern "C" void kernel_launch(void* const* d_in, const int* in_sizes, int n_in,
                              void* d_out, int out_size, void* d_ws, size_t ws_size,
                              hipStream_t stream) {
    (void)n_in; (void)out_size; (void)ws_size;
    const float* x   = (const float*)d_in[0];
    const int*   ei  = (const int*)d_in[1];
    const float* W1  = (const float*)d_in[2];
    const float* as1 = (const float*)d_in[3];
    const float* ad1 = (const float*)d_in[4];
    const float* b1  = (const float*)d_in[5];
    const float* W2  = (const float*)d_in[6];
    const float* as2 = (const float*)d_in[7];
    const float* ad2 = (const float*)d_in[8];
    const float* b2  = (const float*)d_in[9];
    float* out = (float*)d_out;

    const int N = in_sizes[0] / 512;
    const int E = in_sizes[1] / 2;

    char* p = (char*)d_ws;
    auto alloc = [&](size_t bytes) -> char* {
        char* r = p; p += (bytes + 255) & ~(size_t)255; return r;
    };
    float* h1    = (float*)alloc((size_t)N * 64 * 4);
    float* x2    = (float*)alloc((size_t)N * 64 * 4);
    float* h2    = h1;                 // overlay: h1 dead after k_agg1
    float* sc1s  = (float*)alloc((size_t)N * 8 * 4);
    float* sc1d  = (float*)alloc((size_t)N * 8 * 4);
    float* sc2s  = (float*)alloc((size_t)N * 4);
    float* sc2d  = (float*)alloc((size_t)N * 4);
    int*   deg   = (int*)alloc((size_t)N * 4);
    int*   cursor= (int*)alloc((size_t)N * 4);
    int*   indptr= (int*)alloc((size_t)(N + 1) * 4);
    int*   csr   = (int*)alloc((size_t)(E + N) * 4);
    int*   bsum  = (int*)alloc(64 * 4);
    int*   bpre  = (int*)alloc(64 * 4);
    unsigned short* W1t = (unsigned short*)alloc(64 * 512 * 2);

    const int B = (N + CHUNK - 1) / CHUNK;     // 49 <= 64

    // CSR build
    k_init_deg<<<(N + 255) / 256, 256, 0, stream>>>(deg, N);
    k_count_p<<<1024, 256, 0, stream>>>(ei, deg, E, N);
    k_scan1  <<<B, 256, 0, stream>>>(deg, bsum, N);
    k_scan2  <<<1, 64, 0, stream>>>(bsum, bpre, B);
    k_scan3  <<<B, 256, 0, stream>>>(deg, bpre, indptr, cursor, N);
    k_fill_p <<<1024, 256, 0, stream>>>(ei, cursor, csr, E, N);

    // conv1 (MFMA bf16 GEMM)
    k_prepW<<<(64 * 512 + 255) / 256, 256, 0, stream>>>(W1, W1t);
    gemm1_mfma<<<(N + 127) / 128, 256, 0, stream>>>(x, W1t, h1, N);
    k_sc1 <<<(N * 8 + 255) / 256, 256, 0, stream>>>(h1, as1, ad1, sc1s, sc1d, N);
    k_agg1<<<(N + 3) / 4, 256, 0, stream>>>(h1, sc1s, sc1d, indptr, csr, b1, x2, N);

    // conv2 (fp32 GEMM, K=64)
    gemm_n64<64><<<(N + 63) / 64, 256, 0, stream>>>(x2, W2, h2, N, 64);
    k_sc2 <<<(N + 3) / 4, 256, 0, stream>>>(h2, as2, ad2, sc2s, sc2d, N);
    k_agg2<<<(N + 3) / 4, 256, 0, stream>>>(h2, sc2s, sc2d, indptr, csr, b2, out, N);
}

// Round 5
// 671.958 us; speedup vs baseline: 1.3535x; 1.0765x over previous
//
#include <hip/hip_runtime.h>
#include <cstdint>
#include <cstddef>

// Problem constants (from reference): IN=512, H=8, C=8, HID=64, OUT=64
#define LEAKY 0.2f
#define NEG_INF -3.402823466e38f
static const int CHUNK = 2048;   // scan chunk per block (256 thr * 8)

typedef __attribute__((ext_vector_type(8))) short short8;
typedef __attribute__((ext_vector_type(4))) float floatx4;

__device__ __forceinline__ float dot4(float4 a, float4 b) {
    return a.x * b.x + a.y * b.y + a.z * b.z + a.w * b.w;
}

__device__ __forceinline__ unsigned short f2bf(float f) {   // RNE float->bf16
    unsigned u = __float_as_uint(f);
    u += 0x7fffu + ((u >> 16) & 1u);
    return (unsigned short)(u >> 16);
}
__device__ __forceinline__ float bf2f(unsigned short u) {
    return __uint_as_float(((unsigned)u) << 16);
}

// ---------------------------------------------------------------- CSR build
__global__ __launch_bounds__(256) void k_init_deg(int* __restrict__ deg, int Nn) {
    int i = blockIdx.x * 256 + threadIdx.x;
    if (i < Nn) deg[i] = 1;              // self-loop
}

// XCD-partitioned count: partition p (= blockIdx&7) owns dst in [lo,hi).
__global__ __launch_bounds__(256) void k_count_p(const int* __restrict__ ei, int* __restrict__ deg,
                                                 int E, int Nn) {
    int part = blockIdx.x & 7;
    int lo = (int)((long long)Nn * part >> 3);
    int hi = (int)((long long)Nn * (part + 1) >> 3);
    int nthr = (gridDim.x >> 3) * 256;
    int tid = (blockIdx.x >> 3) * 256 + threadIdx.x;
    for (int e = tid; e < E; e += nthr) {
        int d = ei[E + e];
        if (d >= lo && d < hi) atomicAdd(&deg[d], 1);
    }
}

__global__ __launch_bounds__(256) void k_scan1(const int* __restrict__ deg, int* __restrict__ bsum, int Nn) {
    __shared__ int sm[256];
    int b = blockIdx.x, t = threadIdx.x;
    int s = 0;
    int i0 = b * CHUNK + t * 8;
#pragma unroll
    for (int j = 0; j < 8; ++j) { int i = i0 + j; if (i < Nn) s += deg[i]; }
    sm[t] = s;
    __syncthreads();
    for (int o = 128; o; o >>= 1) { if (t < o) sm[t] += sm[t + o]; __syncthreads(); }
    if (t == 0) bsum[b] = sm[0];
}

__global__ void k_scan2(const int* __restrict__ bsum, int* __restrict__ bpre, int B) {
    int l = threadIdx.x;            // 64 threads, B <= 64
    int v = (l < B) ? bsum[l] : 0;
    int inc = v;
#pragma unroll
    for (int o = 1; o < 64; o <<= 1) { int u = __shfl_up(inc, o); if (l >= o) inc += u; }
    if (l < B) bpre[l] = inc - v;   // exclusive
}

__global__ __launch_bounds__(256) void k_scan3(const int* __restrict__ deg, const int* __restrict__ bpre,
                                               int* __restrict__ indptr, int* __restrict__ cursor, int Nn) {
    __shared__ int wsum[4];
    int b = blockIdx.x, t = threadIdx.x, lane = t & 63, w = t >> 6;
    int i0 = b * CHUNK + t * 8;
    int d[8]; int s = 0;
#pragma unroll
    for (int j = 0; j < 8; ++j) { int i = i0 + j; d[j] = (i < Nn) ? deg[i] : 0; s += d[j]; }
    int inc = s;
#pragma unroll
    for (int o = 1; o < 64; o <<= 1) { int u = __shfl_up(inc, o); if (lane >= o) inc += u; }
    if (lane == 63) wsum[w] = inc;
    __syncthreads();
    int wofs = 0;
    for (int k = 0; k < w; ++k) wofs += wsum[k];
    int base = bpre[b] + wofs + (inc - s);
    int run = 0;
#pragma unroll
    for (int j = 0; j < 8; ++j) {
        int i = i0 + j;
        if (i < Nn) {
            int v = base + run;
            indptr[i] = v; cursor[i] = v;
            run += d[j];
            if (i == Nn - 1) indptr[Nn] = v + d[j];
        }
    }
}

// XCD-partitioned fill: one XCD owns each csr region (see round-2 note).
__global__ __launch_bounds__(256) void k_fill_p(const int* __restrict__ ei, int* __restrict__ cursor,
                                                int* __restrict__ csr, int E, int Nn) {
    int part = blockIdx.x & 7;
    int lo = (int)((long long)Nn * part >> 3);
    int hi = (int)((long long)Nn * (part + 1) >> 3);
    int nthr = (gridDim.x >> 3) * 256;
    int tid = (blockIdx.x >> 3) * 256 + threadIdx.x;
    int tot = E + Nn;
    for (int idx = tid; idx < tot; idx += nthr) {
        int d = (idx < E) ? ei[E + idx] : idx - E;
        if (d >= lo && d < hi) {
            int s = (idx < E) ? ei[idx] : idx - E;
            int slot = atomicAdd(&cursor[d], 1);
            csr[slot] = s;
        }
    }
}

// ---------------------------------------------------------------- W1 -> bf16 transposed [64][512]
__global__ __launch_bounds__(256) void k_prepW(const float* __restrict__ W1, unsigned short* __restrict__ W1t) {
    int i = blockIdx.x * 256 + threadIdx.x;      // i over 64*512
    if (i >= 64 * 512) return;
    int n = i >> 9, k = i & 511;
    W1t[i] = f2bf(W1[k * 64 + n]);               // coalesced write, cached read
}

// ---------------------------------------------------------------- MFMA GEMM1: h1bf[M,64] = bf16(x[M,512] @ W1)
// 128x64 block tile, 16x16x32 bf16 MFMA, fp32 accumulate, bf16 output.
__global__ __launch_bounds__(256) void gemm1_mfma(const float* __restrict__ A, const unsigned short* __restrict__ W1t,
                                                  unsigned short* __restrict__ C, int M) {
    __shared__ __align__(16) unsigned short As[128][40];   // 80B row stride: 16B-aligned, 2-way banks
    __shared__ __align__(16) unsigned short Bs[64][40];
    int t = threadIdx.x;
    int w = t >> 6, l = t & 63;
    int quad = l >> 4, lm = l & 15;
    int row0 = blockIdx.x * 128;

    floatx4 acc[2][4] = {};

    for (int k0 = 0; k0 < 512; k0 += 32) {
#pragma unroll
        for (int j = 0; j < 4; ++j) {
            int f = t + 256 * j;
            int r = f >> 3, c4 = f & 7;
            int rg = row0 + r; if (rg >= M) rg = M - 1;
            float4 v = *(const float4*)(A + (size_t)rg * 512 + k0 + c4 * 4);
            ushort4 b; b.x = f2bf(v.x); b.y = f2bf(v.y); b.z = f2bf(v.z); b.w = f2bf(v.w);
            *(ushort4*)&As[r][c4 * 4] = b;
        }
        {
            int n = t >> 2, seg = t & 3;
            *(uint4*)&Bs[n][seg * 8] = *(const uint4*)(W1t + (size_t)n * 512 + k0 + seg * 8);
        }
        __syncthreads();

        short8 af[2], bfm[4];
#pragma unroll
        for (int tm = 0; tm < 2; ++tm) {
            int m = w * 32 + tm * 16 + lm;
            af[tm] = *(const short8*)&As[m][quad * 8];
        }
#pragma unroll
        for (int tn = 0; tn < 4; ++tn) {
            int n = tn * 16 + lm;
            bfm[tn] = *(const short8*)&Bs[n][quad * 8];
        }
#pragma unroll
        for (int tm = 0; tm < 2; ++tm)
#pragma unroll
            for (int tn = 0; tn < 4; ++tn)
                acc[tm][tn] = __builtin_amdgcn_mfma_f32_16x16x32_bf16(af[tm], bfm[tn], acc[tm][tn], 0, 0, 0);
        __syncthreads();
    }

    // epilogue: C/D layout col=lane&15, row=quad*4+reg ; emit bf16
#pragma unroll
    for (int tm = 0; tm < 2; ++tm) {
#pragma unroll
        for (int r = 0; r < 4; ++r) {
            int row = row0 + w * 32 + tm * 16 + quad * 4 + r;
            if (row < M) {
#pragma unroll
                for (int tn = 0; tn < 4; ++tn)
                    C[(size_t)row * 64 + tn * 16 + lm] = f2bf(acc[tm][tn][r]);
            }
        }
    }
}

// ---------------------------------------------------------------- SGEMM Cbf[M,64] = bf16(A[M,K] @ B[K,64]) (fp32 math, conv2)
template <int KB>
__global__ __launch_bounds__(256) void gemm_n64(const float* __restrict__ A, const float* __restrict__ B,
                                                unsigned short* __restrict__ C, int M, int K) {
    __shared__ float As[KB][68];
    __shared__ float Bs[KB][68];
    int tid = threadIdx.x;
    int row0 = blockIdx.x * 64;
    int tx = tid & 15, ty = tid >> 4;
    float acc[4][4] = {};
    for (int k0 = 0; k0 < K; k0 += KB) {
#pragma unroll
        for (int j = 0; j < (64 * KB) / (256 * 4); ++j) {
            int f = tid + 256 * j;
            int r = f / (KB / 4);
            int c4 = f % (KB / 4);
            int rg = row0 + r; if (rg >= M) rg = M - 1;
            float4 v = *(const float4*)(A + (size_t)rg * K + k0 + c4 * 4);
            As[c4 * 4 + 0][r] = v.x; As[c4 * 4 + 1][r] = v.y;
            As[c4 * 4 + 2][r] = v.z; As[c4 * 4 + 3][r] = v.w;
        }
#pragma unroll
        for (int j = 0; j < (KB * 64) / (256 * 4); ++j) {
            int f = tid + 256 * j;
            int kk = f / 16, c4 = f % 16;
            *(float4*)&Bs[kk][c4 * 4] = *(const float4*)(B + (size_t)(k0 + kk) * 64 + c4 * 4);
        }
        __syncthreads();
#pragma unroll
        for (int kk = 0; kk < KB; ++kk) {
            float4 a = *(const float4*)&As[kk][ty * 4];
            float4 b = *(const float4*)&Bs[kk][tx * 4];
            float av[4] = {a.x, a.y, a.z, a.w};
            float bv[4] = {b.x, b.y, b.z, b.w};
#pragma unroll
            for (int i = 0; i < 4; ++i)
#pragma unroll
                for (int j = 0; j < 4; ++j) acc[i][j] += av[i] * bv[j];
        }
        __syncthreads();
    }
#pragma unroll
    for (int i = 0; i < 4; ++i) {
        int rg = row0 + ty * 4 + i;
        if (rg < M) {
            ushort4 b; b.x = f2bf(acc[i][0]); b.y = f2bf(acc[i][1]);
            b.z = f2bf(acc[i][2]); b.w = f2bf(acc[i][3]);
            *(ushort4*)(C + (size_t)rg * 64 + tx * 4) = b;
        }
    }
}

// ---------------------------------------------------------------- attention half-scores (bf16 h inputs)
__global__ __launch_bounds__(256) void k_sc1(const unsigned short* __restrict__ h1, const float* __restrict__ as1,
                                             const float* __restrict__ ad1, float* __restrict__ scs,
                                             float* __restrict__ scd, int Nn) {
    int i = blockIdx.x * 256 + threadIdx.x;   // i = node*8 + head
    if (i >= Nn * 8) return;
    int h = i & 7;
    ushort4 p0 = *(const ushort4*)(h1 + (size_t)i * 8);
    ushort4 p1 = *(const ushort4*)(h1 + (size_t)i * 8 + 4);
    float4 v0 = make_float4(bf2f(p0.x), bf2f(p0.y), bf2f(p0.z), bf2f(p0.w));
    float4 v1 = make_float4(bf2f(p1.x), bf2f(p1.y), bf2f(p1.z), bf2f(p1.w));
    const float4* asp = (const float4*)(as1 + h * 8);
    const float4* adp = (const float4*)(ad1 + h * 8);
    scs[i] = dot4(v0, asp[0]) + dot4(v1, asp[1]);
    scd[i] = dot4(v0, adp[0]) + dot4(v1, adp[1]);
}

__global__ __launch_bounds__(256) void k_sc2(const unsigned short* __restrict__ h2, const float* __restrict__ as2,
                                             const float* __restrict__ ad2, float* __restrict__ scs,
                                             float* __restrict__ scd, int Nn) {
    int wave = (blockIdx.x * 256 + threadIdx.x) >> 6;
    int lane = threadIdx.x & 63;
    if (wave >= Nn) return;
    float v = bf2f(h2[(size_t)wave * 64 + lane]);
    float ss = v * as2[lane], sd = v * ad2[lane];
#pragma unroll
    for (int o = 32; o; o >>= 1) { ss += __shfl_xor(ss, o); sd += __shfl_xor(sd, o); }
    if (lane == 0) { scs[wave] = ss; scd[wave] = sd; }
}

// ---------------------------------------------------------------- conv1 aggregation (8 heads x 8 ch) -> elu -> x2
// bf16 h gather, 2 edges per iteration (half-wave each), lane = channel pair.
__global__ __launch_bounds__(256) void k_agg1(const unsigned short* __restrict__ h1, const float* __restrict__ scs,
                                              const float* __restrict__ scd, const int* __restrict__ indptr,
                                              const int* __restrict__ csr, const float* __restrict__ b1,
                                              float* __restrict__ x2, int Nn) {
    int node = (blockIdx.x * 256 + threadIdx.x) >> 6;
    int l = threadIdx.x & 63;
    if (node >= Nn) return;
    int h8 = l & 7, grp = l >> 3;       // ex-computation role: edge-in-subbatch grp, head h8
    int sub = l >> 5, c2 = l & 31;      // gather role: half-wave sub, channel pair c2
    int head2 = c2 >> 2;                // head of channels {2c2, 2c2+1}
    int start = indptr[node], end = indptr[node + 1];
    float sd = scd[node * 8 + h8];

    // pass 1: per-head max, 8 slots per iteration (lane-parallel)
    float mx = NEG_INF;
    for (int base = start; base < end; base += 8) {
        int slot = base + grp;
        int s = csr[slot < end ? slot : start];
        float v = scs[s * 8 + h8] + sd;
        v = v > 0.f ? v : LEAKY * v;
        mx = fmaxf(mx, (slot < end) ? v : NEG_INF);
    }
#pragma unroll
    for (int o = 8; o < 64; o <<= 1) mx = fmaxf(mx, __shfl_xor(mx, o));
    // lane l holds max for head h8 = l&7

    // pass 2: ex lane-parallel per 8-edge sub-batch; gather 2 edges/iter
    float dsum = 0.f, acc0 = 0.f, acc1 = 0.f;
    for (int base = start; base < end; base += 64) {
        int e = base + l;
        int s64 = csr[e < end ? e : start];
        int cnt = min(64, end - base);
        int nb = (cnt + 7) >> 3;
        for (int b = 0; b < nb; ++b) {
            int slot = base + b * 8 + grp;
            int sb = __shfl(s64, b * 8 + grp);
            float v = scs[sb * 8 + h8] + sd;
            v = v > 0.f ? v : LEAKY * v;
            float ex = (slot < end) ? __expf(v - mx) : 0.f;   // lane L: edge L>>3, head L&7
            dsum += ex;
#pragma unroll
            for (int j = 0; j < 8; j += 2) {
                int jj = j + sub;                              // this half-wave's edge
                float exv = __shfl(ex, (jj << 3) | head2);     // ex[edge jj][head2] (0 if padded)
                int s = __shfl(s64, b * 8 + jj);
                unsigned hp = *(const unsigned*)(h1 + (size_t)s * 64 + c2 * 2);
                acc0 += exv * bf2f((unsigned short)(hp & 0xffffu));
                acc1 += exv * bf2f((unsigned short)(hp >> 16));
            }
        }
    }
#pragma unroll
    for (int o = 8; o < 64; o <<= 1) dsum += __shfl_xor(dsum, o);   // lane l: dsum for head l&7
    acc0 += __shfl_xor(acc0, 32);
    acc1 += __shfl_xor(acc1, 32);      // both halves now hold full sums for channels 2c2, 2c2+1
    float dh = __shfl(dsum, head2);    // dsum for head2
    float inv = 1.f / (dh + 1e-16f);

    float o0 = acc0 * inv + b1[c2 * 2];
    float o1 = acc1 * inv + b1[c2 * 2 + 1];
    o0 = o0 > 0.f ? o0 : expm1f(o0);   // elu
    o1 = o1 > 0.f ? o1 : expm1f(o1);
    if (sub == 0) {
        float2 r = make_float2(o0, o1);
        *(float2*)&x2[(size_t)node * 64 + c2 * 2] = r;
    }
}

// ---------------------------------------------------------------- conv2 aggregation (1 head) -> log_softmax -> out
__global__ __launch_bounds__(256) void k_agg2(const unsigned short* __restrict__ h2, const float* __restrict__ scs,
                                              const float* __restrict__ scd, const int* __restrict__ indptr,
                                              const int* __restrict__ csr, const float* __restrict__ b2,
                                              float* __restrict__ out, int Nn) {
    int node = (blockIdx.x * 256 + threadIdx.x) >> 6;
    int l = threadIdx.x & 63;
    if (node >= Nn) return;
    int sub = l >> 5, c2 = l & 31;
    int start = indptr[node], end = indptr[node + 1];
    float sd = scd[node];

    // pass 1: max, 64 slots per iteration
    float mx = NEG_INF;
    for (int base = start; base < end; base += 64) {
        int e = base + l;
        int s = csr[e < end ? e : start];
        float v = scs[s] + sd;
        v = v > 0.f ? v : LEAKY * v;
        mx = fmaxf(mx, (e < end) ? v : NEG_INF);
    }
#pragma unroll
    for (int o = 32; o; o >>= 1) mx = fmaxf(mx, __shfl_xor(mx, o));

    // pass 2: ex lane-parallel; gather 2 edges/iter, lane = channel pair
    float dsum = 0.f, acc0 = 0.f, acc1 = 0.f;
    for (int base = start; base < end; base += 64) {
        int e = base + l;
        int s64 = csr[e < end ? e : start];
        float v = scs[s64] + sd;
        v = v > 0.f ? v : LEAKY * v;
        float ex = (e < end) ? __expf(v - mx) : 0.f;
        dsum += ex;
        int cnt = min(64, end - base);
        for (int j = 0; j < cnt; j += 2) {
            int jj = j + sub;
            float exv = __shfl(ex, jj);    // 0 for jj >= cnt (padded lanes)
            int s = __shfl(s64, jj);
            unsigned hp = *(const unsigned*)(h2 + (size_t)s * 64 + c2 * 2);
            acc0 += exv * bf2f((unsigned short)(hp & 0xffffu));
            acc1 += exv * bf2f((unsigned short)(hp >> 16));
        }
    }
#pragma unroll
    for (int o = 32; o; o >>= 1) dsum += __shfl_xor(dsum, o);
    acc0 += __shfl_xor(acc0, 32);
    acc1 += __shfl_xor(acc1, 32);      // full sums, both halves duplicate
    float inv = 1.f / (dsum + 1e-16f);
    float o0 = acc0 * inv + b2[c2 * 2];
    float o1 = acc1 * inv + b2[c2 * 2 + 1];

    // log_softmax over 64 channels (2 per lane, within each 32-lane half)
    float m2 = fmaxf(o0, o1);
#pragma unroll
    for (int d = 16; d; d >>= 1) m2 = fmaxf(m2, __shfl_xor(m2, d));
    float e0 = __expf(o0 - m2), e1 = __expf(o1 - m2);
    float se = e0 + e1;
#pragma unroll
    for (int d = 16; d; d >>= 1) se += __shfl_xor(se, d);
    float ls = __logf(se);
    if (sub == 0) {
        float2 r = make_float2(o0 - m2 - ls, o1 - m2 - ls);
        *(float2*)&out[(size_t)node * 64 + c2 * 2] = r;
    }
}

// ---------------------------------------------------------------- launch
extern "C" void kernel_launch(void* const* d_in, const int* in_sizes, int n_in,
                              void* d_out, int out_size, void* d_ws, size_t ws_size,
                              hipStream_t stream) {
    (void)n_in; (void)out_size; (void)ws_size;
    const float* x   = (const float*)d_in[0];
    const int*   ei  = (const int*)d_in[1];
    const float* W1  = (const float*)d_in[2];
    const float* as1 = (const float*)d_in[3];
    const float* ad1 = (const float*)d_in[4];
    const float* b1  = (const float*)d_in[5];
    const float* W2  = (const float*)d_in[6];
    const float* as2 = (const float*)d_in[7];
    const float* ad2 = (const float*)d_in[8];
    const float* b2  = (const float*)d_in[9];
    float* out = (float*)d_out;

    const int N = in_sizes[0] / 512;
    const int E = in_sizes[1] / 2;

    char* p = (char*)d_ws;
    auto alloc = [&](size_t bytes) -> char* {
        char* r = p; p += (bytes + 255) & ~(size_t)255; return r;
    };
    unsigned short* h1bf = (unsigned short*)alloc((size_t)N * 64 * 2);
    float* x2    = (float*)alloc((size_t)N * 64 * 4);
    unsigned short* h2bf = h1bf;       // overlay: h1bf dead after k_agg1
    float* sc1s  = (float*)alloc((size_t)N * 8 * 4);
    float* sc1d  = (float*)alloc((size_t)N * 8 * 4);
    float* sc2s  = (float*)alloc((size_t)N * 4);
    float* sc2d  = (float*)alloc((size_t)N * 4);
    int*   deg   = (int*)alloc((size_t)N * 4);
    int*   cursor= (int*)alloc((size_t)N * 4);
    int*   indptr= (int*)alloc((size_t)(N + 1) * 4);
    int*   csr   = (int*)alloc((size_t)(E + N) * 4);
    int*   bsum  = (int*)alloc(64 * 4);
    int*   bpre  = (int*)alloc(64 * 4);
    unsigned short* W1t = (unsigned short*)alloc(64 * 512 * 2);

    const int B = (N + CHUNK - 1) / CHUNK;     // 49 <= 64

    // CSR build
    k_init_deg<<<(N + 255) / 256, 256, 0, stream>>>(deg, N);
    k_count_p<<<1024, 256, 0, stream>>>(ei, deg, E, N);
    k_scan1  <<<B, 256, 0, stream>>>(deg, bsum, N);
    k_scan2  <<<1, 64, 0, stream>>>(bsum, bpre, B);
    k_scan3  <<<B, 256, 0, stream>>>(deg, bpre, indptr, cursor, N);
    k_fill_p <<<1024, 256, 0, stream>>>(ei, cursor, csr, E, N);

    // conv1 (MFMA bf16 GEMM -> bf16 h1)
    k_prepW<<<(64 * 512 + 255) / 256, 256, 0, stream>>>(W1, W1t);
    gemm1_mfma<<<(N + 127) / 128, 256, 0, stream>>>(x, W1t, h1bf, N);
    k_sc1 <<<(N * 8 + 255) / 256, 256, 0, stream>>>(h1bf, as1, ad1, sc1s, sc1d, N);
    k_agg1<<<(N + 3) / 4, 256, 0, stream>>>(h1bf, sc1s, sc1d, indptr, csr, b1, x2, N);

    // conv2 (fp32 GEMM -> bf16 h2)
    gemm_n64<64><<<(N + 63) / 64, 256, 0, stream>>>(x2, W2, h2bf, N, 64);
    k_sc2 <<<(N + 3) / 4, 256, 0, stream>>>(h2bf, as2, ad2, sc2s, sc2d, N);
    k_agg2<<<(N + 3) / 4, 256, 0, stream>>>(h2bf, sc2s, sc2d, indptr, csr, b2, out, N);
}

// Round 6
// 655.291 us; speedup vs baseline: 1.3880x; 1.0254x over previous
//
#include <hip/hip_runtime.h>
#include <cstdint>
#include <cstddef>

// Problem constants (from reference): IN=512, H=8, C=8, HID=64, OUT=64
#define LEAKY 0.2f
#define NEG_INF -3.402823466e38f
static const int CHUNK = 2048;   // scan chunk per block (256 thr * 8)

typedef __attribute__((ext_vector_type(8))) short short8;
typedef __attribute__((ext_vector_type(4))) float floatx4;

__device__ __forceinline__ float dot4(float4 a, float4 b) {
    return a.x * b.x + a.y * b.y + a.z * b.z + a.w * b.w;
}

__device__ __forceinline__ unsigned short f2bf(float f) {   // RNE float->bf16
    unsigned u = __float_as_uint(f);
    u += 0x7fffu + ((u >> 16) & 1u);
    return (unsigned short)(u >> 16);
}
__device__ __forceinline__ float bf2f(unsigned short u) {
    return __uint_as_float(((unsigned)u) << 16);
}
__device__ __forceinline__ float bflo(unsigned u) { return __uint_as_float(u << 16); }
__device__ __forceinline__ float bfhi(unsigned u) { return __uint_as_float(u & 0xffff0000u); }

// ---------------------------------------------------------------- CSR build
__global__ __launch_bounds__(256) void k_init_deg(int* __restrict__ deg, int Nn) {
    int i = blockIdx.x * 256 + threadIdx.x;
    if (i < Nn) deg[i] = 1;              // self-loop
}

// XCD-partitioned count: partition p (= blockIdx&7) owns dst in [lo,hi).
__global__ __launch_bounds__(256) void k_count_p(const int* __restrict__ ei, int* __restrict__ deg,
                                                 int E, int Nn) {
    int part = blockIdx.x & 7;
    int lo = (int)((long long)Nn * part >> 3);
    int hi = (int)((long long)Nn * (part + 1) >> 3);
    int nthr = (gridDim.x >> 3) * 256;
    int tid = (blockIdx.x >> 3) * 256 + threadIdx.x;
    for (int e = tid; e < E; e += nthr) {
        int d = ei[E + e];
        if (d >= lo && d < hi) atomicAdd(&deg[d], 1);
    }
}

__global__ __launch_bounds__(256) void k_scan1(const int* __restrict__ deg, int* __restrict__ bsum, int Nn) {
    __shared__ int sm[256];
    int b = blockIdx.x, t = threadIdx.x;
    int s = 0;
    int i0 = b * CHUNK + t * 8;
#pragma unroll
    for (int j = 0; j < 8; ++j) { int i = i0 + j; if (i < Nn) s += deg[i]; }
    sm[t] = s;
    __syncthreads();
    for (int o = 128; o; o >>= 1) { if (t < o) sm[t] += sm[t + o]; __syncthreads(); }
    if (t == 0) bsum[b] = sm[0];
}

__global__ void k_scan2(const int* __restrict__ bsum, int* __restrict__ bpre, int B) {
    int l = threadIdx.x;            // 64 threads, B <= 64
    int v = (l < B) ? bsum[l] : 0;
    int inc = v;
#pragma unroll
    for (int o = 1; o < 64; o <<= 1) { int u = __shfl_up(inc, o); if (l >= o) inc += u; }
    if (l < B) bpre[l] = inc - v;   // exclusive
}

__global__ __launch_bounds__(256) void k_scan3(const int* __restrict__ deg, const int* __restrict__ bpre,
                                               int* __restrict__ indptr, int* __restrict__ cursor, int Nn) {
    __shared__ int wsum[4];
    int b = blockIdx.x, t = threadIdx.x, lane = t & 63, w = t >> 6;
    int i0 = b * CHUNK + t * 8;
    int d[8]; int s = 0;
#pragma unroll
    for (int j = 0; j < 8; ++j) { int i = i0 + j; d[j] = (i < Nn) ? deg[i] : 0; s += d[j]; }
    int inc = s;
#pragma unroll
    for (int o = 1; o < 64; o <<= 1) { int u = __shfl_up(inc, o); if (lane >= o) inc += u; }
    if (lane == 63) wsum[w] = inc;
    __syncthreads();
    int wofs = 0;
    for (int k = 0; k < w; ++k) wofs += wsum[k];
    int base = bpre[b] + wofs + (inc - s);
    int run = 0;
#pragma unroll
    for (int j = 0; j < 8; ++j) {
        int i = i0 + j;
        if (i < Nn) {
            int v = base + run;
            indptr[i] = v; cursor[i] = v;
            run += d[j];
            if (i == Nn - 1) indptr[Nn] = v + d[j];
        }
    }
}

// XCD-partitioned fill: one XCD owns each csr region (see round-2 note).
__global__ __launch_bounds__(256) void k_fill_p(const int* __restrict__ ei, int* __restrict__ cursor,
                                                int* __restrict__ csr, int E, int Nn) {
    int part = blockIdx.x & 7;
    int lo = (int)((long long)Nn * part >> 3);
    int hi = (int)((long long)Nn * (part + 1) >> 3);
    int nthr = (gridDim.x >> 3) * 256;
    int tid = (blockIdx.x >> 3) * 256 + threadIdx.x;
    int tot = E + Nn;
    for (int idx = tid; idx < tot; idx += nthr) {
        int d = (idx < E) ? ei[E + idx] : idx - E;
        if (d >= lo && d < hi) {
            int s = (idx < E) ? ei[idx] : idx - E;
            int slot = atomicAdd(&cursor[d], 1);
            csr[slot] = s;
        }
    }
}

// ---------------------------------------------------------------- W1 -> bf16 transposed [64][512]
__global__ __launch_bounds__(256) void k_prepW(const float* __restrict__ W1, unsigned short* __restrict__ W1t) {
    int i = blockIdx.x * 256 + threadIdx.x;      // i over 64*512
    if (i >= 64 * 512) return;
    int n = i >> 9, k = i & 511;
    W1t[i] = f2bf(W1[k * 64 + n]);               // coalesced write, cached read
}

// ---------------------------------------------------------------- MFMA GEMM1: h1bf[M,64] = bf16(x[M,512] @ W1)
__global__ __launch_bounds__(256) void gemm1_mfma(const float* __restrict__ A, const unsigned short* __restrict__ W1t,
                                                  unsigned short* __restrict__ C, int M) {
    __shared__ __align__(16) unsigned short As[128][40];   // 80B row stride: 16B-aligned, 2-way banks
    __shared__ __align__(16) unsigned short Bs[64][40];
    int t = threadIdx.x;
    int w = t >> 6, l = t & 63;
    int quad = l >> 4, lm = l & 15;
    int row0 = blockIdx.x * 128;

    floatx4 acc[2][4] = {};

    for (int k0 = 0; k0 < 512; k0 += 32) {
#pragma unroll
        for (int j = 0; j < 4; ++j) {
            int f = t + 256 * j;
            int r = f >> 3, c4 = f & 7;
            int rg = row0 + r; if (rg >= M) rg = M - 1;
            float4 v = *(const float4*)(A + (size_t)rg * 512 + k0 + c4 * 4);
            ushort4 b; b.x = f2bf(v.x); b.y = f2bf(v.y); b.z = f2bf(v.z); b.w = f2bf(v.w);
            *(ushort4*)&As[r][c4 * 4] = b;
        }
        {
            int n = t >> 2, seg = t & 3;
            *(uint4*)&Bs[n][seg * 8] = *(const uint4*)(W1t + (size_t)n * 512 + k0 + seg * 8);
        }
        __syncthreads();

        short8 af[2], bfm[4];
#pragma unroll
        for (int tm = 0; tm < 2; ++tm) {
            int m = w * 32 + tm * 16 + lm;
            af[tm] = *(const short8*)&As[m][quad * 8];
        }
#pragma unroll
        for (int tn = 0; tn < 4; ++tn) {
            int n = tn * 16 + lm;
            bfm[tn] = *(const short8*)&Bs[n][quad * 8];
        }
#pragma unroll
        for (int tm = 0; tm < 2; ++tm)
#pragma unroll
            for (int tn = 0; tn < 4; ++tn)
                acc[tm][tn] = __builtin_amdgcn_mfma_f32_16x16x32_bf16(af[tm], bfm[tn], acc[tm][tn], 0, 0, 0);
        __syncthreads();
    }

    // epilogue: C/D layout col=lane&15, row=quad*4+reg ; emit bf16
#pragma unroll
    for (int tm = 0; tm < 2; ++tm) {
#pragma unroll
        for (int r = 0; r < 4; ++r) {
            int row = row0 + w * 32 + tm * 16 + quad * 4 + r;
            if (row < M) {
#pragma unroll
                for (int tn = 0; tn < 4; ++tn)
                    C[(size_t)row * 64 + tn * 16 + lm] = f2bf(acc[tm][tn][r]);
            }
        }
    }
}

// ---------------------------------------------------------------- SGEMM Cbf[M,64] = bf16(A[M,K] @ B[K,64]) (fp32 math, conv2)
template <int KB>
__global__ __launch_bounds__(256) void gemm_n64(const float* __restrict__ A, const float* __restrict__ B,
                                                unsigned short* __restrict__ C, int M, int K) {
    __shared__ float As[KB][68];
    __shared__ float Bs[KB][68];
    int tid = threadIdx.x;
    int row0 = blockIdx.x * 64;
    int tx = tid & 15, ty = tid >> 4;
    float acc[4][4] = {};
    for (int k0 = 0; k0 < K; k0 += KB) {
#pragma unroll
        for (int j = 0; j < (64 * KB) / (256 * 4); ++j) {
            int f = tid + 256 * j;
            int r = f / (KB / 4);
            int c4 = f % (KB / 4);
            int rg = row0 + r; if (rg >= M) rg = M - 1;
            float4 v = *(const float4*)(A + (size_t)rg * K + k0 + c4 * 4);
            As[c4 * 4 + 0][r] = v.x; As[c4 * 4 + 1][r] = v.y;
            As[c4 * 4 + 2][r] = v.z; As[c4 * 4 + 3][r] = v.w;
        }
#pragma unroll
        for (int j = 0; j < (KB * 64) / (256 * 4); ++j) {
            int f = tid + 256 * j;
            int kk = f / 16, c4 = f % 16;
            *(float4*)&Bs[kk][c4 * 4] = *(const float4*)(B + (size_t)(k0 + kk) * 64 + c4 * 4);
        }
        __syncthreads();
#pragma unroll
        for (int kk = 0; kk < KB; ++kk) {
            float4 a = *(const float4*)&As[kk][ty * 4];
            float4 b = *(const float4*)&Bs[kk][tx * 4];
            float av[4] = {a.x, a.y, a.z, a.w};
            float bv[4] = {b.x, b.y, b.z, b.w};
#pragma unroll
            for (int i = 0; i < 4; ++i)
#pragma unroll
                for (int j = 0; j < 4; ++j) acc[i][j] += av[i] * bv[j];
        }
        __syncthreads();
    }
#pragma unroll
    for (int i = 0; i < 4; ++i) {
        int rg = row0 + ty * 4 + i;
        if (rg < M) {
            ushort4 b; b.x = f2bf(acc[i][0]); b.y = f2bf(acc[i][1]);
            b.z = f2bf(acc[i][2]); b.w = f2bf(acc[i][3]);
            *(ushort4*)(C + (size_t)rg * 64 + tx * 4) = b;
        }
    }
}

// ---------------------------------------------------------------- attention half-scores (bf16 h inputs)
__global__ __launch_bounds__(256) void k_sc1(const unsigned short* __restrict__ h1, const float* __restrict__ as1,
                                             const float* __restrict__ ad1, float* __restrict__ scs,
                                             float* __restrict__ scd, int Nn) {
    int i = blockIdx.x * 256 + threadIdx.x;   // i = node*8 + head
    if (i >= Nn * 8) return;
    int h = i & 7;
    ushort4 p0 = *(const ushort4*)(h1 + (size_t)i * 8);
    ushort4 p1 = *(const ushort4*)(h1 + (size_t)i * 8 + 4);
    float4 v0 = make_float4(bf2f(p0.x), bf2f(p0.y), bf2f(p0.z), bf2f(p0.w));
    float4 v1 = make_float4(bf2f(p1.x), bf2f(p1.y), bf2f(p1.z), bf2f(p1.w));
    const float4* asp = (const float4*)(as1 + h * 8);
    const float4* adp = (const float4*)(ad1 + h * 8);
    scs[i] = dot4(v0, asp[0]) + dot4(v1, asp[1]);
    scd[i] = dot4(v0, adp[0]) + dot4(v1, adp[1]);
}

__global__ __launch_bounds__(256) void k_sc2(const unsigned short* __restrict__ h2, const float* __restrict__ as2,
                                             const float* __restrict__ ad2, float* __restrict__ scs,
                                             float* __restrict__ scd, int Nn) {
    int wave = (blockIdx.x * 256 + threadIdx.x) >> 6;
    int lane = threadIdx.x & 63;
    if (wave >= Nn) return;
    float v = bf2f(h2[(size_t)wave * 64 + lane]);
    float ss = v * as2[lane], sd = v * ad2[lane];
#pragma unroll
    for (int o = 32; o; o >>= 1) { ss += __shfl_xor(ss, o); sd += __shfl_xor(sd, o); }
    if (lane == 0) { scs[wave] = ss; scd[wave] = sd; }
}

// ---------------------------------------------------------------- conv1 aggregation (8 heads x 8 ch) -> elu -> x2
// One wave per node. Lane l: edge-in-batch g=l>>3, head/channel-octet h8=l&7.
// One uint4 gather covers 8 edges x 128B rows per wave-issue (8x MLP vs scalar).
__global__ __launch_bounds__(256) void k_agg1(const unsigned short* __restrict__ h1, const float* __restrict__ scs,
                                              const float* __restrict__ scd, const int* __restrict__ indptr,
                                              const int* __restrict__ csr, const float* __restrict__ b1,
                                              float* __restrict__ x2, int Nn) {
    int node = (blockIdx.x * 256 + threadIdx.x) >> 6;
    int l = threadIdx.x & 63;
    if (node >= Nn) return;
    int h8 = l & 7, grp = l >> 3;
    int start = indptr[node], end = indptr[node + 1];
    float sd = scd[node * 8 + h8];

    // pass 1: per-head max, 8 slots per iteration (lane-parallel)
    float mx = NEG_INF;
    for (int base = start; base < end; base += 8) {
        int slot = base + grp;
        int s = csr[slot < end ? slot : start];
        float v = scs[s * 8 + h8] + sd;
        v = v > 0.f ? v : LEAKY * v;
        mx = fmaxf(mx, (slot < end) ? v : NEG_INF);
    }
#pragma unroll
    for (int o = 8; o < 64; o <<= 1) mx = fmaxf(mx, __shfl_xor(mx, o));
    // lane l: mx for head h8

    // pass 2: lane l handles edge grp of each 8-batch, channels of head h8.
    // exv needed = ex[edge grp][head h8] = lane's OWN ex. sb reused for gather.
    float dsum = 0.f;
    float acc8[8] = {};
    for (int base = start; base < end; base += 64) {
        int e = base + l;
        int s64 = csr[e < end ? e : start];
        int cnt = min(64, end - base);
        int nb = (cnt + 7) >> 3;
#pragma unroll 2
        for (int b = 0; b < nb; ++b) {
            int slot = base + b * 8 + grp;
            int sb = __shfl(s64, b * 8 + grp);
            float v = scs[sb * 8 + h8] + sd;
            v = v > 0.f ? v : LEAKY * v;
            float ex = (slot < end) ? __expf(v - mx) : 0.f;
            dsum += ex;
            uint4 q = *(const uint4*)(h1 + (size_t)sb * 64 + h8 * 8);   // 8 bf16 channels
            acc8[0] += ex * bflo(q.x); acc8[1] += ex * bfhi(q.x);
            acc8[2] += ex * bflo(q.y); acc8[3] += ex * bfhi(q.y);
            acc8[4] += ex * bflo(q.z); acc8[5] += ex * bfhi(q.z);
            acc8[6] += ex * bflo(q.w); acc8[7] += ex * bfhi(q.w);
        }
    }
    // reduce over edge-group axis (bits 3..5); head axis stays per-lane
#pragma unroll
    for (int o = 8; o < 64; o <<= 1) {
        dsum += __shfl_xor(dsum, o);
#pragma unroll
        for (int k = 0; k < 8; ++k) acc8[k] += __shfl_xor(acc8[k], o);
    }
    if (grp == 0) {                      // lanes 0..7: h8 = l, write channels 8l..8l+7
        float inv = 1.f / (dsum + 1e-16f);
        float4 ba = *((const float4*)b1 + h8 * 2);
        float4 bb = *((const float4*)b1 + h8 * 2 + 1);
        float o0 = acc8[0] * inv + ba.x, o1 = acc8[1] * inv + ba.y;
        float o2 = acc8[2] * inv + ba.z, o3 = acc8[3] * inv + ba.w;
        float o4 = acc8[4] * inv + bb.x, o5 = acc8[5] * inv + bb.y;
        float o6 = acc8[6] * inv + bb.z, o7 = acc8[7] * inv + bb.w;
        o0 = o0 > 0.f ? o0 : expm1f(o0); o1 = o1 > 0.f ? o1 : expm1f(o1);
        o2 = o2 > 0.f ? o2 : expm1f(o2); o3 = o3 > 0.f ? o3 : expm1f(o3);
        o4 = o4 > 0.f ? o4 : expm1f(o4); o5 = o5 > 0.f ? o5 : expm1f(o5);
        o6 = o6 > 0.f ? o6 : expm1f(o6); o7 = o7 > 0.f ? o7 : expm1f(o7);
        float* dst = x2 + (size_t)node * 64 + h8 * 8;
        *(float4*)dst = make_float4(o0, o1, o2, o3);
        *(float4*)(dst + 4) = make_float4(o4, o5, o6, o7);
    }
}

// ---------------------------------------------------------------- conv2 aggregation (1 head) -> log_softmax -> out
__global__ __launch_bounds__(256) void k_agg2(const unsigned short* __restrict__ h2, const float* __restrict__ scs,
                                              const float* __restrict__ scd, const int* __restrict__ indptr,
                                              const int* __restrict__ csr, const float* __restrict__ b2,
                                              float* __restrict__ out, int Nn) {
    int node = (blockIdx.x * 256 + threadIdx.x) >> 6;
    int l = threadIdx.x & 63;
    if (node >= Nn) return;
    int g = l >> 3, c8 = l & 7;
    int start = indptr[node], end = indptr[node + 1];
    float sd = scd[node];

    // pass 1: max, 64 slots per iteration
    float mx = NEG_INF;
    for (int base = start; base < end; base += 64) {
        int e = base + l;
        int s = csr[e < end ? e : start];
        float v = scs[s] + sd;
        v = v > 0.f ? v : LEAKY * v;
        mx = fmaxf(mx, (e < end) ? v : NEG_INF);
    }
#pragma unroll
    for (int o = 32; o; o >>= 1) mx = fmaxf(mx, __shfl_xor(mx, o));

    // pass 2: ex lane-parallel; gather 8 edges/iter (lane: edge g, octet c8)
    float dsum = 0.f;
    float acc8[8] = {};
    for (int base = start; base < end; base += 64) {
        int e = base + l;
        int s64 = csr[e < end ? e : start];
        float v = scs[s64] + sd;
        v = v > 0.f ? v : LEAKY * v;
        float ex = (e < end) ? __expf(v - mx) : 0.f;
        dsum += ex;
        int cnt = min(64, end - base);
        int nb = (cnt + 7) >> 3;
#pragma unroll 2
        for (int b = 0; b < nb; ++b) {
            float exv = __shfl(ex, b * 8 + g);
            int sb = __shfl(s64, b * 8 + g);
            uint4 q = *(const uint4*)(h2 + (size_t)sb * 64 + c8 * 8);
            acc8[0] += exv * bflo(q.x); acc8[1] += exv * bfhi(q.x);
            acc8[2] += exv * bflo(q.y); acc8[3] += exv * bfhi(q.y);
            acc8[4] += exv * bflo(q.z); acc8[5] += exv * bfhi(q.z);
            acc8[6] += exv * bflo(q.w); acc8[7] += exv * bfhi(q.w);
        }
    }
#pragma unroll
    for (int o = 32; o; o >>= 1) dsum += __shfl_xor(dsum, o);   // full reduce
#pragma unroll
    for (int o = 8; o < 64; o <<= 1)
#pragma unroll
        for (int k = 0; k < 8; ++k) acc8[k] += __shfl_xor(acc8[k], o);

    float inv = 1.f / (dsum + 1e-16f);
    float4 ba = *((const float4*)b2 + c8 * 2);
    float4 bb = *((const float4*)b2 + c8 * 2 + 1);
    float ov[8];
    ov[0] = acc8[0] * inv + ba.x; ov[1] = acc8[1] * inv + ba.y;
    ov[2] = acc8[2] * inv + ba.z; ov[3] = acc8[3] * inv + ba.w;
    ov[4] = acc8[4] * inv + bb.x; ov[5] = acc8[5] * inv + bb.y;
    ov[6] = acc8[6] * inv + bb.z; ov[7] = acc8[7] * inv + bb.w;

    // log_softmax over 64 channels: local max/sum over 8, xor-reduce over c8 axis (bits 0..2)
    float m2 = ov[0];
#pragma unroll
    for (int k = 1; k < 8; ++k) m2 = fmaxf(m2, ov[k]);
#pragma unroll
    for (int o = 1; o < 8; o <<= 1) m2 = fmaxf(m2, __shfl_xor(m2, o));
    float se = 0.f;
#pragma unroll
    for (int k = 0; k < 8; ++k) se += __expf(ov[k] - m2);
#pragma unroll
    for (int o = 1; o < 8; o <<= 1) se += __shfl_xor(se, o);
    float ls = m2 + __logf(se);
    if (g == 0) {                        // lanes 0..7: c8 = l, write channels 8l..8l+7
        float* dst = out + (size_t)node * 64 + c8 * 8;
        *(float4*)dst = make_float4(ov[0] - ls, ov[1] - ls, ov[2] - ls, ov[3] - ls);
        *(float4*)(dst + 4) = make_float4(ov[4] - ls, ov[5] - ls, ov[6] - ls, ov[7] - ls);
    }
}

// ---------------------------------------------------------------- launch
extern "C" void kernel_launch(void* const* d_in, const int* in_sizes, int n_in,
                              void* d_out, int out_size, void* d_ws, size_t ws_size,
                              hipStream_t stream) {
    (void)n_in; (void)out_size; (void)ws_size;
    const float* x   = (const float*)d_in[0];
    const int*   ei  = (const int*)d_in[1];
    const float* W1  = (const float*)d_in[2];
    const float* as1 = (const float*)d_in[3];
    const float* ad1 = (const float*)d_in[4];
    const float* b1  = (const float*)d_in[5];
    const float* W2  = (const float*)d_in[6];
    const float* as2 = (const float*)d_in[7];
    const float* ad2 = (const float*)d_in[8];
    const float* b2  = (const float*)d_in[9];
    float* out = (float*)d_out;

    const int N = in_sizes[0] / 512;
    const int E = in_sizes[1] / 2;

    char* p = (char*)d_ws;
    auto alloc = [&](size_t bytes) -> char* {
        char* r = p; p += (bytes + 255) & ~(size_t)255; return r;
    };
    unsigned short* h1bf = (unsigned short*)alloc((size_t)N * 64 * 2);
    float* x2    = (float*)alloc((size_t)N * 64 * 4);
    unsigned short* h2bf = h1bf;       // overlay: h1bf dead after k_agg1
    float* sc1s  = (float*)alloc((size_t)N * 8 * 4);
    float* sc1d  = (float*)alloc((size_t)N * 8 * 4);
    float* sc2s  = (float*)alloc((size_t)N * 4);
    float* sc2d  = (float*)alloc((size_t)N * 4);
    int*   deg   = (int*)alloc((size_t)N * 4);
    int*   cursor= (int*)alloc((size_t)N * 4);
    int*   indptr= (int*)alloc((size_t)(N + 1) * 4);
    int*   csr   = (int*)alloc((size_t)(E + N) * 4);
    int*   bsum  = (int*)alloc(64 * 4);
    int*   bpre  = (int*)alloc(64 * 4);
    unsigned short* W1t = (unsigned short*)alloc(64 * 512 * 2);

    const int B = (N + CHUNK - 1) / CHUNK;     // 49 <= 64

    // CSR build
    k_init_deg<<<(N + 255) / 256, 256, 0, stream>>>(deg, N);
    k_count_p<<<1024, 256, 0, stream>>>(ei, deg, E, N);
    k_scan1  <<<B, 256, 0, stream>>>(deg, bsum, N);
    k_scan2  <<<1, 64, 0, stream>>>(bsum, bpre, B);
    k_scan3  <<<B, 256, 0, stream>>>(deg, bpre, indptr, cursor, N);
    k_fill_p <<<1024, 256, 0, stream>>>(ei, cursor, csr, E, N);

    // conv1 (MFMA bf16 GEMM -> bf16 h1)
    k_prepW<<<(64 * 512 + 255) / 256, 256, 0, stream>>>(W1, W1t);
    gemm1_mfma<<<(N + 127) / 128, 256, 0, stream>>>(x, W1t, h1bf, N);
    k_sc1 <<<(N * 8 + 255) / 256, 256, 0, stream>>>(h1bf, as1, ad1, sc1s, sc1d, N);
    k_agg1<<<(N + 3) / 4, 256, 0, stream>>>(h1bf, sc1s, sc1d, indptr, csr, b1, x2, N);

    // conv2 (fp32 GEMM -> bf16 h2)
    gemm_n64<64><<<(N + 63) / 64, 256, 0, stream>>>(x2, W2, h2bf, N, 64);
    k_sc2 <<<(N + 3) / 4, 256, 0, stream>>>(h2bf, as2, ad2, sc2s, sc2d, N);
    k_agg2<<<(N + 3) / 4, 256, 0, stream>>>(h2bf, sc2s, sc2d, indptr, csr, b2, out, N);
}